// Round 3
// baseline (19821.593 us; speedup 1.0000x reference)
//
#include <hip/hip_runtime.h>
#include <hip/hip_bf16.h>

typedef unsigned int u32;
typedef _Float16 h16;
typedef __attribute__((ext_vector_type(2))) _Float16 h16x2;

union U4 { uint4 u; h16x2 p[4]; };

static __device__ __forceinline__ float sigm(float x){ return 1.0f / (1.0f + __expf(-x)); }
static __device__ __forceinline__ float ftanh(float x){ return 1.0f - 2.0f/(1.0f + __expf(2.0f*x)); }
static __device__ __forceinline__ h16x2 f2h2(float a, float b){
  h16x2 r; r[0] = (h16)a; r[1] = (h16)b; return r;
}
// Pin a packed-f16 pair into an arch-VGPR (defeats AGPR-parking / remat).
static __device__ __forceinline__ void pinv(h16x2 &x){
  u32 t = __builtin_bit_cast(u32, x);
  asm volatile("" : "+v"(t));
  x = __builtin_bit_cast(h16x2, t);
}

#if defined(__has_builtin)
#if __has_builtin(__builtin_amdgcn_fdot2)
#define FDOT2_NATIVE 1
#endif
#endif
static __device__ __forceinline__ float fdot2(h16x2 a, h16x2 b, float c){
#ifdef FDOT2_NATIVE
  return __builtin_amdgcn_fdot2(a, b, c, false);
#else
  return c + (float)a[0]*(float)b[0] + (float)a[1]*(float)b[1];
#endif
}

#define NT 4096
#define OUTS_OFF 45056

// ---------------- K0: weight conversions (f32 -> f16, packed layouts) ----
__global__ __launch_bounds__(256) void k0_prep(
    const float* __restrict__ noteWh, const float* __restrict__ voiceWh,
    const float* __restrict__ outWi,  const float* __restrict__ Wfc,
    h16* __restrict__ WhF, h16* __restrict__ outWiF, h16* __restrict__ WfcKF)
{
  const int NWH = 4*1024*256;     // 1048576
  const int NOW = 512*1416;       // 724992
  const int NFC = 10*1416;        // 14160
  for (int i = blockIdx.x*256 + threadIdx.x; i < NWH + NOW + NFC; i += gridDim.x*256) {
    if (i < NWH) {
      int dir = i >> 18;
      int rem = i & 262143;
      const float* src = (dir < 2) ? noteWh : voiceWh;
      WhF[i] = (h16)src[((dir & 1) << 18) + rem];
    } else if (i < NWH + NOW) {
      int j = i - NWH;
      int r = j / 1416, c = j - r*1416;
      float v = 0.f;
      if (c < 1408) v = outWi[(size_t)r*1424 + c];
      else if (c < 1411) v = outWi[(size_t)r*1424 + 1421 + (c-1408)];
      outWiF[j] = (h16)v;
    } else {
      int j = i - NWH - NOW;
      int r = j / 1416, c = j - r*1416;
      float v = 0.f;
      if (c < 1408) v = Wfc[(size_t)r*1552 + 128 + c];
      else if (c < 1411) v = Wfc[(size_t)r*1552 + 1549 + (c-1408)];
      WfcKF[j] = (h16)v;
    }
  }
}

// ---------------- K1: note/voice input gates: pre = b + Wi @ x ------------
// preNV layout: [dir][t][e*4 + gate]  (gate-interleaved so K2 loads one u2)
__global__ __launch_bounds__(256) void k1_xgates(
    const float* __restrict__ x,
    const float* __restrict__ noteWi, const float* __restrict__ noteB,
    const float* __restrict__ voiceWi, const float* __restrict__ voiceB,
    h16* __restrict__ preNV)
{
  const int dir = blockIdx.y;
  const int t0  = blockIdx.x * 16;
  const int tid = threadIdx.x;
  __shared__ float xs[16][80];
  for (int i = tid; i < 16*78; i += 256) {
    int tt = i / 78, j = i - tt*78;
    xs[tt][j] = x[(size_t)(t0+tt)*78 + j];
  }
  __syncthreads();
  const float* Wi = (dir < 2) ? noteWi : voiceWi;
  const float* B  = (dir < 2) ? noteB  : voiceB;
  const int dw = dir & 1;
  for (int gc = 0; gc < 4; ++gc) {
    int g = gc*256 + tid;
    const float* row = Wi + ((size_t)dw*1024 + g)*78;
    float bias = B[dw*1024 + g];
    float acc[16];
#pragma unroll
    for (int tt=0; tt<16; ++tt) acc[tt] = bias;
#pragma unroll 6
    for (int j=0; j<78; ++j) {
      float w = row[j];
#pragma unroll
      for (int tt=0; tt<16; ++tt)
        acc[tt] += w*xs[tt][j];
    }
#pragma unroll
    for (int tt=0; tt<16; ++tt)
      preNV[((size_t)dir*NT + (t0+tt))*1024 + (tid*4 + gc)] = (h16)acc[tt];
  }
}

// ---------------- K2: note/voice recurrences (4 dirs, 1 block each) -------
// v3: 256 threads (4 waves = 1 wave/SIMD -> ~512-VGPR budget).
//   Thread e owns ALL FOUR gates of element e over ALL 256 columns:
//     cols [0,192)   in VGPRs: 4 gates x 96 h16x2 = 384 regs (pinned),
//     cols [192,256) in LDS (128 KiB, lane-dense, conflict-free).
//   Full dot product per thread -> NO cross-lane reduction, no shuffles,
//   one barrier per step (ping-pong hb). DS pipe per step per CU:
//   4 waves x (32 broadcast hb reads + 32 weight reads) = 256 insts,
//   128 KB moved (~1024 bank-cycles); VALU 512 fdot2/thread (~1024
//   cyc/SIMD). pre gates fetched as one 8B load, prefetched 1 step.
__global__ __launch_bounds__(256, 1) void k2_nvrec(
    const h16* __restrict__ WhF,
    const h16* __restrict__ preNV,
    float* __restrict__ note_h,
    float* __restrict__ voice_h,
    float* __restrict__ out_noteh)
{
  const int dir = blockIdx.x;
  const int e = threadIdx.x;          // element 0..255
  const h16* Wb = WhF + (size_t)dir*1024*256;

  // Register weights: cols 0..191, gates 0..3 (i,f,g,o)
  h16x2 w[4][96];
#pragma unroll
  for (int g=0; g<4; ++g) {
    const h16* row = Wb + (size_t)(g*256 + e)*256;
#pragma unroll
    for (int cb=0; cb<24; ++cb) {
      U4 a; a.u = *(const uint4*)(row + cb*8);
#pragma unroll
      for (int i=0;i<4;++i) w[g][cb*4+i] = a.p[i];
    }
  }
#pragma unroll
  for (int g=0; g<4; ++g)
#pragma unroll
    for (int c=0;c<96;++c) pinv(w[g][c]);

  // LDS weights: cols 192..255, lane-dense: [(blk*4+g)][e][8]
  __shared__ __align__(16) h16 Wl[8*4*256*8];   // 128 KiB
  __shared__ __align__(16) h16 hb[2][256];
#pragma unroll
  for (int blk=0; blk<8; ++blk)
#pragma unroll
    for (int g=0; g<4; ++g) {
      const h16* src = Wb + (size_t)(g*256 + e)*256 + 192 + blk*8;
      *(uint4*)&Wl[(size_t)(((blk*4+g)*256 + e))*8] = *(const uint4*)src;
    }
  hb[0][e] = (h16)0.f;
  float cc = 0.f;
  __syncthreads();

  const bool fwd = ((dir & 1) == 0);
  const bool isNote = (dir < 2);
  float* hout = isNote ? note_h : voice_h;
  const int half = (dir & 1) * 256;
  const h16* pre = preNV + (size_t)dir*NT*1024;
  int cur = 0;
  const int step = fwd ? 1 : -1;
  int t = fwd ? 0 : NT-1;

  union PU { uint2 u; h16 h[4]; };
  PU pv_n; pv_n.u = *(const uint2*)(pre + (size_t)t*1024 + e*4);

  for (int it = 0; it < NT; ++it, t += step) {
    PU pv = pv_n;
    if (it+1 < NT) pv_n.u = *(const uint2*)(pre + (size_t)(t+step)*1024 + e*4);

    float ac[4][2] = {{0.f,0.f},{0.f,0.f},{0.f,0.f},{0.f,0.f}};
    // register-resident columns (0..191)
#pragma unroll
    for (int cb=0; cb<24; ++cb) {
      U4 hh; hh.u = *(const uint4*)&hb[cur][cb*8];
#pragma unroll
      for (int i=0;i<4;++i) {
        ac[0][i&1] = fdot2(w[0][cb*4+i], hh.p[i], ac[0][i&1]);
        ac[1][i&1] = fdot2(w[1][cb*4+i], hh.p[i], ac[1][i&1]);
        ac[2][i&1] = fdot2(w[2][cb*4+i], hh.p[i], ac[2][i&1]);
        ac[3][i&1] = fdot2(w[3][cb*4+i], hh.p[i], ac[3][i&1]);
      }
    }
    // LDS-resident columns (192..255)
#pragma unroll
    for (int blk=0; blk<8; ++blk) {
      U4 hh; hh.u = *(const uint4*)&hb[cur][192 + blk*8];
#pragma unroll
      for (int g=0; g<4; ++g) {
        U4 wv; wv.u = *(const uint4*)&Wl[(size_t)(((blk*4+g)*256 + e))*8];
#pragma unroll
        for (int i=0;i<4;++i) ac[g][i&1] = fdot2(wv.p[i], hh.p[i], ac[g][i&1]);
      }
    }
    // cell (full dot product per thread -> no cross-lane exchange)
    float gi = (float)pv.h[0] + ac[0][0] + ac[0][1];
    float gf = (float)pv.h[1] + ac[1][0] + ac[1][1];
    float gg = (float)pv.h[2] + ac[2][0] + ac[2][1];
    float go = (float)pv.h[3] + ac[3][0] + ac[3][1];
    cc = sigm(gf)*cc + sigm(gi)*ftanh(gg);
    float h = sigm(go)*ftanh(cc);
    hb[cur^1][e] = (h16)h;
    hout[(size_t)t*512 + half + e] = h;
    if (isNote) out_noteh[(size_t)t*512 + half + e] = h;
    cur ^= 1;
    __syncthreads();   // new h visible; ping-pong makes one barrier safe
  }
}

// ---------------- K3: beat segment attention ------------------------------
__global__ __launch_bounds__(256) void k3_battn(
    const float* __restrict__ note_h,
    const float* __restrict__ Wba, const float* __restrict__ bba,
    float* __restrict__ beat_nodes)
{
  const int b = blockIdx.x;
  const int tid = threadIdx.x;
  __shared__ float nh[8][512];
  for (int i = tid; i < 8*512; i += 256)
    nh[i>>9][i&511] = note_h[(size_t)b*8*512 + i];
  __syncthreads();
  for (int dc = 0; dc < 2; ++dc) {
    int d = dc*256 + tid;
    const float* wr = Wba + (size_t)d*512;
    float bb = bba[d];
    float l[8];
#pragma unroll
    for (int n=0;n<8;++n) l[n]=bb;
#pragma unroll 4
    for (int j=0; j<512; ++j) {
      float w = wr[j];
#pragma unroll
      for (int n=0;n<8;++n) l[n] += w*nh[n][j];
    }
    float m = l[0];
#pragma unroll
    for (int n=1;n<8;++n) m = fmaxf(m, l[n]);
    float s = 0.f, o = 0.f;
#pragma unroll
    for (int n=0;n<8;++n) { float e = __expf(l[n]-m); s += e; o += e*nh[n][d]; }
    beat_nodes[(size_t)b*512 + d] = o / s;
  }
}

// ---------------- K4: beat input gates ------------------------------------
__global__ __launch_bounds__(256) void k4_bgates(
    const float* __restrict__ beat_nodes,
    const float* __restrict__ beatWi, const float* __restrict__ beatB,
    float* __restrict__ preB)
{
  const int dir = blockIdx.y, b0 = blockIdx.x*8, tid = threadIdx.x;
  __shared__ float nd[8][512];
  for (int i = tid; i < 8*512; i += 256)
    nd[i>>9][i&511] = beat_nodes[(size_t)b0*512 + i];
  __syncthreads();
  for (int gc = 0; gc < 2; ++gc) {
    int g = gc*256 + tid;
    const float* wr = beatWi + ((size_t)dir*512 + g)*512;
    float bias = beatB[dir*512 + g];
    float acc[8];
#pragma unroll
    for (int n=0;n<8;++n) acc[n]=bias;
#pragma unroll 4
    for (int j=0; j<512; ++j) {
      float w = wr[j];
#pragma unroll
      for (int n=0;n<8;++n) acc[n] += w*nd[n][j];
    }
#pragma unroll
    for (int n=0;n<8;++n)
      preB[((size_t)dir*512 + (b0+n))*512 + g] = acc[n];
  }
}

// ---------------- K5: beat recurrence (H=128, weights in regs) ------------
__global__ __launch_bounds__(512) void k5_brec(
    const float* __restrict__ beatWh,
    const float* __restrict__ preB,
    float* __restrict__ beat_h)
{
  const int dir = blockIdx.x, L = threadIdx.x;
  h16x2 w[64];
  {
    const float2* p = (const float2*)(beatWh + ((size_t)dir*512 + L)*128);
#pragma unroll
    for (int c=0;c<64;++c){
      float2 v = p[c];
      w[c] = f2h2(v.x, v.y);
    }
  }
#pragma unroll
  for (int c=0;c<64;++c) pinv(w[c]);
  __shared__ __align__(16) h16 hb[128];
  __shared__ float gl[512];
  if (L < 128) hb[L] = (h16)0.f;
  float cc = 0.f;
  __syncthreads();
  const bool fwd = (dir == 0);
  for (int it = 0; it < 512; ++it) {
    const int t = fwd ? it : 511 - it;
    float pr = preB[((size_t)dir*512 + t)*512 + L];
    float ac[4] = {0.f,0.f,0.f,0.f};
#pragma unroll
    for (int c=0;c<16;++c){
      U4 hh; hh.u = *(const uint4*)&hb[c*8];
#pragma unroll
      for (int i=0;i<4;++i) ac[i] = fdot2(w[c*4+i], hh.p[i], ac[i]);
    }
    gl[L] = pr + ((ac[0]+ac[1]) + (ac[2]+ac[3]));
    __syncthreads();
    if (L < 128) {
      float gi = gl[L], gf = gl[L+128], gg = gl[L+256], go = gl[L+384];
      cc = sigm(gf)*cc + sigm(gi)*ftanh(gg);
      float h = sigm(go)*ftanh(cc);
      hb[L] = (h16)h;
      beat_h[(size_t)t*256 + dir*128 + L] = h;
    }
    __syncthreads();
  }
}

// ---------------- K6: measure segment attention ---------------------------
__global__ __launch_bounds__(256) void k6_mattn(
    const float* __restrict__ beat_h,
    const float* __restrict__ Wma, const float* __restrict__ bma,
    float* __restrict__ meas_nodes)
{
  const int m = blockIdx.x, tid = threadIdx.x;
  __shared__ float bh[4][256];
  for (int i = tid; i < 4*256; i += 256)
    bh[i>>8][i&255] = beat_h[(size_t)m*4*256 + i];
  __syncthreads();
  int d = tid;
  const float* wr = Wma + (size_t)d*256;
  float bb = bma[d];
  float l[4];
#pragma unroll
  for (int n=0;n<4;++n) l[n]=bb;
#pragma unroll 4
  for (int j=0; j<256; ++j) {
    float w = wr[j];
#pragma unroll
    for (int n=0;n<4;++n) l[n] += w*bh[n][j];
  }
  float mm = fmaxf(fmaxf(l[0],l[1]), fmaxf(l[2],l[3]));
  float s = 0.f, o = 0.f;
#pragma unroll
  for (int n=0;n<4;++n) { float e = __expf(l[n]-mm); s += e; o += e*bh[n][d]; }
  meas_nodes[(size_t)m*256 + d] = o / s;
}

// ---------------- K7: measure input gates ---------------------------------
__global__ __launch_bounds__(256) void k7_mgates(
    const float* __restrict__ meas_nodes,
    const float* __restrict__ measWi, const float* __restrict__ measB,
    float* __restrict__ preM)
{
  const int dir = blockIdx.y, m0 = blockIdx.x*8, tid = threadIdx.x;
  __shared__ float nd[8][256];
  for (int i = tid; i < 8*256; i += 256)
    nd[i>>8][i&255] = meas_nodes[(size_t)m0*256 + i];
  __syncthreads();
  int g = tid;
  const float* wr = measWi + ((size_t)dir*256 + g)*256;
  float bias = measB[dir*256 + g];
  float acc[8];
#pragma unroll
  for (int n=0;n<8;++n) acc[n]=bias;
#pragma unroll 4
  for (int j=0; j<256; ++j) {
    float w = wr[j];
#pragma unroll
    for (int n=0;n<8;++n) acc[n] += w*nd[n][j];
  }
#pragma unroll
  for (int n=0;n<8;++n)
    preM[((size_t)dir*128 + (m0+n))*256 + g] = acc[n];
}

// ---------------- K8: measure recurrence (H=64) ---------------------------
__global__ __launch_bounds__(256, 2) void k8_mrec(
    const float* __restrict__ measWh,
    const float* __restrict__ preM,
    float* __restrict__ meas_h)
{
  const int dir = blockIdx.x, L = threadIdx.x;
  h16x2 w[32];
  {
    const float2* p = (const float2*)(measWh + ((size_t)dir*256 + L)*64);
#pragma unroll
    for (int c=0;c<32;++c){
      float2 v = p[c];
      w[c] = f2h2(v.x, v.y);
    }
  }
#pragma unroll
  for (int c=0;c<32;++c) pinv(w[c]);
  __shared__ __align__(16) h16 hb[64];
  __shared__ float gl[256];
  if (L < 64) hb[L] = (h16)0.f;
  float cc = 0.f;
  __syncthreads();
  const bool fwd = (dir == 0);
  for (int it = 0; it < 128; ++it) {
    const int t = fwd ? it : 127 - it;
    float pr = preM[((size_t)dir*128 + t)*256 + L];
    float ac[4] = {0.f,0.f,0.f,0.f};
#pragma unroll
    for (int c=0;c<8;++c){
      U4 hh; hh.u = *(const uint4*)&hb[c*8];
#pragma unroll
      for (int i=0;i<4;++i) ac[i] = fdot2(w[c*4+i], hh.p[i], ac[i]);
    }
    gl[L] = pr + ((ac[0]+ac[1]) + (ac[2]+ac[3]));
    __syncthreads();
    if (L < 64) {
      float gi = gl[L], gf = gl[L+64], gg = gl[L+128], go = gl[L+192];
      cc = sigm(gf)*cc + sigm(gi)*ftanh(gg);
      float h = sigm(go)*ftanh(cc);
      hb[L] = (h16)h;
      meas_h[(size_t)t*128 + dir*64 + L] = h;
    }
    __syncthreads();
  }
}

// ---------------- K9: scan known-part GEMM (pre_out + pre_fc) -------------
__global__ __launch_bounds__(256) void k9_scanpre(
    const float* __restrict__ note_h, const float* __restrict__ voice_h,
    const float* __restrict__ beat_h, const float* __restrict__ meas_h,
    const float* __restrict__ xf,
    const h16* __restrict__ outWiF, const h16* __restrict__ WfcKF,
    const float* __restrict__ outB, const float* __restrict__ bfc,
    float* __restrict__ pre_out, float* __restrict__ pre_fc)
{
  const int t0 = blockIdx.x*8, tid = threadIdx.x;
  __shared__ __align__(16) h16 kn[8][1416];
  const float qpm = xf[5], tp0 = xf[76], tp1 = xf[77];
  for (int i = tid; i < 8*1416; i += 256) {
    int tt = i/1416, c = i - tt*1416;
    int t = t0 + tt;
    float v;
    if (c < 512) v = note_h[(size_t)t*512 + c];
    else if (c < 768) v = beat_h[(size_t)(t>>3)*256 + (c-512)];
    else if (c < 896) v = meas_h[(size_t)(t>>5)*128 + (c-768)];
    else if (c < 1408) v = voice_h[(size_t)t*512 + (c-896)];
    else if (c == 1408) v = qpm;
    else if (c == 1409) v = tp0;
    else if (c == 1410) v = tp1;
    else v = 0.f;
    kn[tt][c] = (h16)v;
  }
  __syncthreads();
  for (int rr = 0; rr < 3; ++rr) {
    int r = (rr < 2) ? (tid + rr*256) : (512 + tid);
    if (rr == 2 && tid >= 10) break;
    const h16* wrow = (r < 512) ? (outWiF + (size_t)r*1416) : (WfcKF + (size_t)(r-512)*1416);
    float bias = (r < 512) ? outB[r] : bfc[r-512];
    float acc[8];
#pragma unroll
    for (int tt=0;tt<8;++tt) acc[tt] = bias;
    for (int cu = 0; cu < 177; ++cu) {
      U4 wv; wv.u = *(const uint4*)(wrow + cu*8);
#pragma unroll
      for (int tt=0; tt<8; ++tt) {
        U4 kv; kv.u = *(const uint4*)&kn[tt][cu*8];
#pragma unroll
        for (int i=0;i<4;++i) acc[tt] = fdot2(wv.p[i], kv.p[i], acc[tt]);
      }
    }
#pragma unroll
    for (int tt=0; tt<8; ++tt) {
      if (r < 512) pre_out[(size_t)(t0+tt)*512 + r] = acc[tt];
      else pre_fc[(size_t)(t0+tt)*16 + (r-512)] = acc[tt];
    }
  }
}

// ---------------- K9b: bt-LSTM known-part gates ---------------------------
__global__ __launch_bounds__(256) void k9b_btpre(
    const float* __restrict__ beat_h, const float* __restrict__ xf,
    const float* __restrict__ btWi, const float* __restrict__ btB,
    float* __restrict__ pre_bt)
{
  const int b0 = blockIdx.x*8, tid = threadIdx.x;
  __shared__ float bh[8][256];
  __shared__ float btv[8][3];
  for (int i = tid; i < 8*256; i += 256)
    bh[i>>8][i&255] = beat_h[(size_t)b0*256 + i];
  if (tid < 24) {
    int n = tid/3, j = tid - n*3;
    btv[n][j] = xf[(size_t)(b0+n)*8*78 + 28 + j];
  }
  __syncthreads();
  const float qpm = xf[5], tp0 = xf[76], tp1 = xf[77];
  for (int gc = 0; gc < 2; ++gc) {
    int g = gc*256 + tid;
    const float* row = btWi + (size_t)g*273;
    float bias = btB[g];
    float acc[8];
#pragma unroll
    for (int n=0;n<8;++n) acc[n]=bias;
#pragma unroll 4
    for (int j = 0; j < 256; ++j) {
      float w = row[j];
#pragma unroll
      for (int n=0;n<8;++n) acc[n] += w*bh[n][j];
    }
    float w257 = row[257], w258 = row[258], w259 = row[259];
    float w260 = row[260], w261 = row[261], w262 = row[262];
#pragma unroll
    for (int n=0;n<8;++n) {
      acc[n] += w257*qpm + w258*tp0 + w259*tp1
              + w260*btv[n][0] + w261*btv[n][1] + w262*btv[n][2];
      pre_bt[(size_t)(b0+n)*512 + g] = acc[n];
    }
  }
}

// ---------------- K10: the grand sequential scan --------------------------
__global__ __launch_bounds__(512) void k10_scan(
    const float* __restrict__ pre_out, const float* __restrict__ pre_fc,
    const float* __restrict__ pre_bt,
    const float* __restrict__ outWh, const float* __restrict__ btWh,
    const float* __restrict__ outWi, const float* __restrict__ btWi,
    const float* __restrict__ Wfc,
    const float* __restrict__ Wta, const float* __restrict__ bta,
    const float* __restrict__ Wt1, const float* __restrict__ bt1,
    const float* __restrict__ Wt2, const float* __restrict__ bt2,
    const float* __restrict__ yf,
    float* __restrict__ out)
{
  const int L = threadIdx.x;
  h16x2 owh[64], btw[64];
  {
    const float2* p = (const float2*)(outWh + (size_t)L*128);
    const float2* q = (const float2*)(btWh + (size_t)L*128);
#pragma unroll
    for (int c=0;c<64;++c){
      float2 a = p[c]; owh[c] = f2h2(a.x, a.y);
      float2 b = q[c]; btw[c] = f2h2(b.x, b.y);
    }
  }
#pragma unroll
  for (int c=0;c<64;++c){ pinv(owh[c]); pinv(btw[c]); }
  float oseq[13];
#pragma unroll
  for (int j=0;j<13;++j) oseq[j] = outWi[(size_t)L*1424 + 1408 + j];
  float btpt = btWi[(size_t)L*273 + 256];
  float btrn[10];
#pragma unroll
  for (int d=0;d<10;++d) btrn[d] = btWi[(size_t)L*273 + 263 + d];

  __shared__ __align__(16) h16 oh16[128];
  __shared__ __align__(16) h16 th16[128];
  __shared__ __align__(16) h16 Wt1f[128*136];  // f16, padded row stride 136
  __shared__ __align__(16) h16 WfcD[10*128];
  __shared__ float gl[512], gb[512];
  __shared__ float pofc[16];
  __shared__ float ptvS;
  __shared__ float buf[8][10];
  __shared__ float rn[10], att[8][10], r1v[128], ytail[10];
  __shared__ float WfcSeq[10][13];
  __shared__ float WtaS[100], btaS[10], Wt2S[128], bt1S[128], bt2S;

  for (int i=L; i<128*128; i+=512) Wt1f[(i>>7)*136 + (i&127)] = (h16)Wt1[i];
  for (int i=L; i<10*128; i+=512)  WfcD[i] = (h16)Wfc[(size_t)(i>>7)*1552 + (i&127)];
  if (L < 100) WtaS[L] = Wta[L];
  if (L < 10)  btaS[L] = bta[L];
  if (L < 128) { Wt2S[L] = Wt2[L]; bt1S[L] = bt1[L]; }
  if (L == 0)  bt2S = bt2[0];
  if (L < 128) { oh16[L] = (h16)0.f; th16[L] = (h16)0.f; }
  if (L < 11) pofc[L] = yf[L];
  if (L >= 11 && L < 16) pofc[L] = 0.f;
  if (L == 0) ptvS = yf[0];
  if (L < 10) ytail[L] = yf[1+L];
  if (L < 80) buf[L/10][L%10] = 0.f;
  if (L < 130) WfcSeq[L/13][L%13] = Wfc[(size_t)(L/13)*1552 + 1536 + (L%13)];
  float oc = 0.f, tc = 0.f;
  const int dD = L >> 2, qD = L & 3;
  float prv  = pre_out[L];                       // prefetched pre_out row t=0
  float prbt = pre_bt[L];                        // prefetched beat 0
  float prfc = (L < 40 && qD == 0) ? pre_fc[dD] : 0.f;
  __syncthreads();

  for (int t = 0; t < NT; ++t) {
    const bool isb = (t & 7) == 0;
    if (isb) {
      if (t == 0) {
        if (L < 10) rn[L] = ytail[L];
      } else {
        if (L < 80) {
          int n = L/10, d = L - n*10;
          float s = btaS[d];
#pragma unroll
          for (int j=0;j<10;++j) s += buf[n][j]*WtaS[d*10 + j];
          att[n][d] = s;
        }
        __syncthreads();
        if (L < 10) {
          float m = att[0][L];
#pragma unroll
          for (int n=1;n<8;++n) m = fmaxf(m, att[n][L]);
          float s = 0.f, acc = 0.f;
#pragma unroll
          for (int n=0;n<8;++n) { float e = __expf(att[n][L]-m); s += e; acc += e*buf[n][L]; }
          rn[L] = acc/s;
        }
      }
      __syncthreads();
    }
    // A: gates (with next-step prefetch)
    {
      float pr = prv;
      if (t+1 < NT) prv = pre_out[(size_t)(t+1)*512 + L];
      float ac[4] = {0.f,0.f,0.f,0.f};
#pragma unroll
      for (int c=0;c<16;++c){
        U4 hh; hh.u = *(const uint4*)&oh16[c*8];
#pragma unroll
        for (int i=0;i<4;++i) ac[i] = fdot2(owh[c*4+i], hh.p[i], ac[i]);
      }
      float a = pr + ((ac[0]+ac[1]) + (ac[2]+ac[3]));
#pragma unroll
      for (int j=0;j<13;++j) a += oseq[j]*pofc[j];
      gl[L] = a;
    }
    if (isb) {
      float pr = prbt + btpt*ptvS;
      if (t+8 < NT) prbt = pre_bt[(size_t)((t>>3)+1)*512 + L];
      float ac[4] = {0.f,0.f,0.f,0.f};
#pragma unroll
      for (int c=0;c<16;++c){
        U4 hh; hh.u = *(const uint4*)&th16[c*8];
#pragma unroll
        for (int i=0;i<4;++i) ac[i] = fdot2(btw[c*4+i], hh.p[i], ac[i]);
      }
      float b = pr + ((ac[0]+ac[1]) + (ac[2]+ac[3]));
#pragma unroll
      for (int d=0;d<10;++d) b += btrn[d]*rn[d];
      gb[L] = b;
    }
    __syncthreads();                       // s1
    // B: cells
    if (L < 128) {
      float gi = gl[L], gf = gl[L+128], gg = gl[L+256], go = gl[L+384];
      oc = sigm(gf)*oc + sigm(gi)*ftanh(gg);
      float nh = sigm(go)*ftanh(oc);
      oh16[L] = (h16)nh;
    } else if (L < 256 && isb) {
      int j = L - 128;
      float gi = gb[j], gf = gb[j+128], gg = gb[j+256], go = gb[j+384];
      tc = sigm(gf)*tc + sigm(gi)*ftanh(gg);
      float nth = sigm(go)*ftanh(tc);
      th16[j] = (h16)nth;
    }
    __syncthreads();                       // s2
    // C1: tempo hidden layer (beat steps; Wt1 f16 in LDS, th16 = f16 nth)
    if (isb) {
      if (L < 128) {
        float ac[4] = {0.f,0.f,0.f,0.f};
        const h16* wrow = &Wt1f[L*136];
#pragma unroll
        for (int k=0;k<16;++k){
          U4 wv; wv.u = *(const uint4*)(wrow + k*8);
          U4 hh; hh.u = *(const uint4*)&th16[k*8];
#pragma unroll
          for (int i=0;i<4;++i) ac[i] = fdot2(wv.p[i], hh.p[i], ac[i]);
        }
        float s = bt1S[L] + ((ac[0]+ac[1]) + (ac[2]+ac[3]));
        r1v[L] = fmaxf(s, 0.f);
      }
      __syncthreads();
    }
    // wave 0: C2 (ptv) + D (out_fc) + E (epilogue) — single-wave, shfl-linked
    if (L < 64) {
      float ptv_l;
      if (isb) {
        float p = Wt2S[L]*r1v[L] + Wt2S[L+64]*r1v[L+64];
#pragma unroll
        for (int sft=32; sft>0; sft>>=1) p += __shfl_xor(p, sft, 64);
        ptv_l = p + bt2S;
        if (L == 0) ptvS = ptv_l;
      } else {
        ptv_l = ptvS;
      }
      // D
      float s = 0.f;
      if (L < 40) {
        const h16* wr = &WfcD[dD*128 + qD*32];
#pragma unroll
        for (int j=0;j<32;++j) s += (float)wr[j] * (float)oh16[qD*32 + j];
      }
      s += __shfl_xor(s, 1, 64);
      s += __shfl_xor(s, 2, 64);
      float e = 0.f;
      if (L < 40 && qD == 0) {
        e = prfc;
#pragma unroll
        for (int j=0;j<13;++j) e += WfcSeq[dD][j]*pofc[j];
        if (t+1 < NT) prfc = pre_fc[(size_t)(t+1)*16 + dD];
      }
      float ofc = s + e;                   // final at lanes 4d, d<10
      // E
      int srcE = (L >= 1 && L < 11) ? 4*(L-1) : ((L >= 11 && L < 13) ? 4*(L-11) : 0);
      float valE = __shfl(ofc, srcE, 64);
      float bval = __shfl(ofc, 4*(L & 15), 64);
      if (L == 0)      { out[(size_t)t*11] = ptv_l; pofc[0] = ptv_l; }
      else if (L < 11) { out[(size_t)t*11 + L] = valE; pofc[L] = valE; }
      else if (L < 13) { pofc[L] = valE; }
      if (L < 10) buf[t & 7][L] = bval;
    }
    __syncthreads();                       // s3
  }
}

// ---------------- launcher ------------------------------------------------
extern "C" void kernel_launch(void* const* d_in, const int* in_sizes, int n_in,
                              void* d_out, int out_size, void* d_ws, size_t ws_size,
                              hipStream_t stream)
{
  const float* x      = (const float*)d_in[0];
  const float* y      = (const float*)d_in[1];
  const float* noteWi = (const float*)d_in[4];
  const float* noteWh = (const float*)d_in[5];
  const float* noteB  = (const float*)d_in[6];
  const float* voiceWi= (const float*)d_in[7];
  const float* voiceWh= (const float*)d_in[8];
  const float* voiceB = (const float*)d_in[9];
  const float* beatWi = (const float*)d_in[10];
  const float* beatWh = (const float*)d_in[11];
  const float* beatB  = (const float*)d_in[12];
  const float* measWi = (const float*)d_in[13];
  const float* measWh = (const float*)d_in[14];
  const float* measB  = (const float*)d_in[15];
  const float* Wba    = (const float*)d_in[16];
  const float* bba    = (const float*)d_in[17];
  const float* Wma    = (const float*)d_in[18];
  const float* bma    = (const float*)d_in[19];
  const float* Wta    = (const float*)d_in[20];
  const float* bta    = (const float*)d_in[21];
  const float* outWi  = (const float*)d_in[22];
  const float* outWh  = (const float*)d_in[23];
  const float* outB   = (const float*)d_in[24];
  const float* Wfc    = (const float*)d_in[25];
  const float* bfc    = (const float*)d_in[26];
  const float* btWi   = (const float*)d_in[27];
  const float* btWh   = (const float*)d_in[28];
  const float* btB    = (const float*)d_in[29];
  const float* Wt1    = (const float*)d_in[30];
  const float* bt1    = (const float*)d_in[31];
  const float* Wt2    = (const float*)d_in[32];
  const float* bt2    = (const float*)d_in[33];

  float* fws = (float*)d_ws;
  float* note_h     = fws + 0;
  float* voice_h    = fws + 2097152;
  float* beat_nodes = fws + 4194304;
  float* preB       = fws + 4456448;
  float* beat_h     = fws + 4980736;
  float* meas_nodes = fws + 5111808;
  float* preM       = fws + 5144576;
  float* meas_h     = fws + 5210112;
  float* pre_out    = fws + 5226496;
  float* pre_fc     = fws + 7323648;
  float* pre_bt     = fws + 7389184;
  h16* hws   = (h16*)(fws + 7651328);
  h16* preNV  = hws;
  h16* WhF    = hws + 16777216;
  h16* outWiF = hws + 17825792;
  h16* WfcKF  = hws + 18550784;

  float* out_outs  = (float*)d_out;
  float* out_noteh = out_outs + OUTS_OFF;

  hipLaunchKernelGGL(k0_prep, dim3(1024), dim3(256), 0, stream,
                     noteWh, voiceWh, outWi, Wfc, WhF, outWiF, WfcKF);
  hipLaunchKernelGGL(k1_xgates, dim3(256,4), dim3(256), 0, stream,
                     x, noteWi, noteB, voiceWi, voiceB, preNV);
  hipLaunchKernelGGL(k2_nvrec, dim3(4), dim3(256), 0, stream,
                     WhF, preNV, note_h, voice_h, out_noteh);
  hipLaunchKernelGGL(k3_battn, dim3(512), dim3(256), 0, stream,
                     note_h, Wba, bba, beat_nodes);
  hipLaunchKernelGGL(k4_bgates, dim3(64,2), dim3(256), 0, stream,
                     beat_nodes, beatWi, beatB, preB);
  hipLaunchKernelGGL(k5_brec, dim3(2), dim3(512), 0, stream,
                     beatWh, preB, beat_h);
  hipLaunchKernelGGL(k6_mattn, dim3(128), dim3(256), 0, stream,
                     beat_h, Wma, bma, meas_nodes);
  hipLaunchKernelGGL(k7_mgates, dim3(16,2), dim3(256), 0, stream,
                     meas_nodes, measWi, measB, preM);
  hipLaunchKernelGGL(k8_mrec, dim3(2), dim3(256), 0, stream,
                     measWh, preM, meas_h);
  hipLaunchKernelGGL(k9b_btpre, dim3(64), dim3(256), 0, stream,
                     beat_h, x, btWi, btB, pre_bt);
  hipLaunchKernelGGL(k9_scanpre, dim3(512), dim3(256), 0, stream,
                     note_h, voice_h, beat_h, meas_h, x, outWiF, WfcKF, outB, bfc, pre_out, pre_fc);
  hipLaunchKernelGGL(k10_scan, dim3(1), dim3(512), 0, stream,
                     pre_out, pre_fc, pre_bt, outWh, btWh, outWi, btWi, Wfc,
                     Wta, bta, Wt1, bt1, Wt2, bt2, y, out_outs);
}

// Round 4
// 14488.611 us; speedup vs baseline: 1.3681x; 1.3681x over previous
//
#include <hip/hip_runtime.h>
#include <hip/hip_bf16.h>

typedef unsigned int u32;
typedef _Float16 h16;
typedef __attribute__((ext_vector_type(2))) _Float16 h16x2;

union U4 { uint4 u; h16x2 p[4]; };

static __device__ __forceinline__ float sigm(float x){ return 1.0f / (1.0f + __expf(-x)); }
static __device__ __forceinline__ float ftanh(float x){ return 1.0f - 2.0f/(1.0f + __expf(2.0f*x)); }
static __device__ __forceinline__ h16x2 f2h2(float a, float b){
  h16x2 r; r[0] = (h16)a; r[1] = (h16)b; return r;
}
// Pin a packed-f16 pair into an arch-VGPR (defeats AGPR-parking / remat).
static __device__ __forceinline__ void pinv(h16x2 &x){
  u32 t = __builtin_bit_cast(u32, x);
  asm volatile("" : "+v"(t));
  x = __builtin_bit_cast(h16x2, t);
}

#if defined(__has_builtin)
#if __has_builtin(__builtin_amdgcn_fdot2)
#define FDOT2_NATIVE 1
#endif
#endif
static __device__ __forceinline__ float fdot2(h16x2 a, h16x2 b, float c){
#ifdef FDOT2_NATIVE
  return __builtin_amdgcn_fdot2(a, b, c, false);
#else
  return c + (float)a[0]*(float)b[0] + (float)a[1]*(float)b[1];
#endif
}

#define NT 4096
#define OUTS_OFF 45056

// ---------------- K0: weight conversions (f32 -> f16, packed layouts) ----
__global__ __launch_bounds__(256) void k0_prep(
    const float* __restrict__ noteWh, const float* __restrict__ voiceWh,
    const float* __restrict__ outWi,  const float* __restrict__ Wfc,
    h16* __restrict__ WhF, h16* __restrict__ outWiF, h16* __restrict__ WfcKF)
{
  const int NWH = 4*1024*256;     // 1048576
  const int NOW = 512*1416;       // 724992
  const int NFC = 10*1416;        // 14160
  for (int i = blockIdx.x*256 + threadIdx.x; i < NWH + NOW + NFC; i += gridDim.x*256) {
    if (i < NWH) {
      int dir = i >> 18;
      int rem = i & 262143;
      const float* src = (dir < 2) ? noteWh : voiceWh;
      WhF[i] = (h16)src[((dir & 1) << 18) + rem];
    } else if (i < NWH + NOW) {
      int j = i - NWH;
      int r = j / 1416, c = j - r*1416;
      float v = 0.f;
      if (c < 1408) v = outWi[(size_t)r*1424 + c];
      else if (c < 1411) v = outWi[(size_t)r*1424 + 1421 + (c-1408)];
      outWiF[j] = (h16)v;
    } else {
      int j = i - NWH - NOW;
      int r = j / 1416, c = j - r*1416;
      float v = 0.f;
      if (c < 1408) v = Wfc[(size_t)r*1552 + 128 + c];
      else if (c < 1411) v = Wfc[(size_t)r*1552 + 1549 + (c-1408)];
      WfcKF[j] = (h16)v;
    }
  }
}

// ---------------- K1: note/voice input gates: pre = b + Wi @ x ------------
// preNV layout: [dir][t][e*4 + gate]  (gate-interleaved so K2 loads one u2)
__global__ __launch_bounds__(256) void k1_xgates(
    const float* __restrict__ x,
    const float* __restrict__ noteWi, const float* __restrict__ noteB,
    const float* __restrict__ voiceWi, const float* __restrict__ voiceB,
    h16* __restrict__ preNV)
{
  const int dir = blockIdx.y;
  const int t0  = blockIdx.x * 16;
  const int tid = threadIdx.x;
  __shared__ float xs[16][80];
  for (int i = tid; i < 16*78; i += 256) {
    int tt = i / 78, j = i - tt*78;
    xs[tt][j] = x[(size_t)(t0+tt)*78 + j];
  }
  __syncthreads();
  const float* Wi = (dir < 2) ? noteWi : voiceWi;
  const float* B  = (dir < 2) ? noteB  : voiceB;
  const int dw = dir & 1;
  for (int gc = 0; gc < 4; ++gc) {
    int g = gc*256 + tid;
    const float* row = Wi + ((size_t)dw*1024 + g)*78;
    float bias = B[dw*1024 + g];
    float acc[16];
#pragma unroll
    for (int tt=0; tt<16; ++tt) acc[tt] = bias;
#pragma unroll 6
    for (int j=0; j<78; ++j) {
      float w = row[j];
#pragma unroll
      for (int tt=0; tt<16; ++tt)
        acc[tt] += w*xs[tt][j];
    }
#pragma unroll
    for (int tt=0; tt<16; ++tt)
      preNV[((size_t)dir*NT + (t0+tt))*1024 + (tid*4 + gc)] = (h16)acc[tt];
  }
}

// ---------------- K2: note/voice recurrences (4 dirs, 1 block each) -------
// Round-2 proven structure (6.5 ms): 512 threads; lane bit5 = column-half hi,
// e = wid*32 + (lane&31). Thread (e,hi) computes ALL FOUR gates of element e
// over 128 columns: 96 cols in VGPRs (192 words), 32 cols in LDS (128 KiB).
// Partials combined with __shfl_xor(.,32); one barrier/step (ping-pong hb).
// waves_per_eu(2,2): occupancy is fixed at 2 waves/EU anyway (8 waves, 1
// block/CU) — telling the allocator lets it keep weights in ARCH VGPRs
// (<=256/wave) instead of ACC-parking them (which costs a v_accvgpr_read
// per parked word per step).
__global__ __launch_bounds__(512) __attribute__((amdgpu_waves_per_eu(2, 2)))
void k2_nvrec(
    const h16* __restrict__ WhF,
    const h16* __restrict__ preNV,
    float* __restrict__ note_h,
    float* __restrict__ voice_h,
    float* __restrict__ out_noteh)
{
  const int dir = blockIdx.x;
  const int L = threadIdx.x;
  const int lane = L & 63;
  const int wid  = L >> 6;           // 0..7
  const int hi   = lane >> 5;        // column half
  const int e    = wid*32 + (lane & 31);   // element 0..255
  const int c0   = hi*128;
  const h16* Wb = WhF + (size_t)dir*1024*256;

  // Register weights: cols c0..c0+95, gates 0..3 (i,f,g,o)
  h16x2 w[4][48];
#pragma unroll
  for (int g=0; g<4; ++g) {
    const h16* row = Wb + (size_t)(g*256 + e)*256 + c0;
#pragma unroll
    for (int cb=0; cb<12; ++cb) {
      U4 a; a.u = *(const uint4*)(row + cb*8);
#pragma unroll
      for (int i=0;i<4;++i) w[g][cb*4+i] = a.p[i];
    }
  }
#pragma unroll
  for (int g=0; g<4; ++g)
#pragma unroll
    for (int c=0;c<48;++c) pinv(w[g][c]);

  // LDS weights: cols c0+96..c0+127, lane-dense: [(cb*4+g)*2+hi][e][8]
  __shared__ __align__(16) h16 Wl[4*4*2*256*8];   // 128 KiB
  __shared__ __align__(16) h16 hb[2][256];
#pragma unroll
  for (int cb=0; cb<4; ++cb)
#pragma unroll
    for (int g=0; g<4; ++g) {
      const h16* src = Wb + (size_t)(g*256 + e)*256 + c0 + 96 + cb*8;
      *(uint4*)&Wl[(size_t)((((cb*4+g)*2 + hi)*256 + e))*8] = *(const uint4*)src;
    }
  if (hi == 0) hb[0][e] = (h16)0.f;
  float cc = 0.f;
  __syncthreads();

  const bool fwd = ((dir & 1) == 0);
  const bool isNote = (dir < 2);
  float* hout = isNote ? note_h : voice_h;
  const int half = (dir & 1) * 256;
  const h16* pre = preNV + (size_t)dir*NT*1024;
  int cur = 0;
  const int step = fwd ? 1 : -1;
  int t = fwd ? 0 : NT-1;

  union PU { uint2 u; h16 h[4]; };
  PU pv_n; pv_n.u = *(const uint2*)(pre + (size_t)t*1024 + e*4);

  for (int it = 0; it < NT; ++it, t += step) {
    PU pv = pv_n;
    if (it+1 < NT) pv_n.u = *(const uint2*)(pre + (size_t)(t+step)*1024 + e*4);

    float ac[4][2] = {{0.f,0.f},{0.f,0.f},{0.f,0.f},{0.f,0.f}};
    // register-resident columns
#pragma unroll
    for (int cb=0; cb<12; ++cb) {
      U4 hh; hh.u = *(const uint4*)&hb[cur][c0 + cb*8];
#pragma unroll
      for (int i=0;i<4;++i) {
        ac[0][i&1] = fdot2(w[0][cb*4+i], hh.p[i], ac[0][i&1]);
        ac[1][i&1] = fdot2(w[1][cb*4+i], hh.p[i], ac[1][i&1]);
        ac[2][i&1] = fdot2(w[2][cb*4+i], hh.p[i], ac[2][i&1]);
        ac[3][i&1] = fdot2(w[3][cb*4+i], hh.p[i], ac[3][i&1]);
      }
    }
    // LDS-resident columns
#pragma unroll
    for (int cb=0; cb<4; ++cb) {
      U4 hh; hh.u = *(const uint4*)&hb[cur][c0 + 96 + cb*8];
#pragma unroll
      for (int g=0; g<4; ++g) {
        U4 wv; wv.u = *(const uint4*)&Wl[(size_t)((((cb*4+g)*2 + hi)*256 + e))*8];
#pragma unroll
        for (int i=0;i<4;++i) ac[g][i&1] = fdot2(wv.p[i], hh.p[i], ac[g][i&1]);
      }
    }
    // combine halves within the wave (lane ^ 32)
    float g4[4];
#pragma unroll
    for (int g=0; g<4; ++g) {
      float s = ac[g][0] + ac[g][1];
      s += __shfl_xor(s, 32, 64);
      g4[g] = s;
    }
    // cell (both halves compute identically; hi==0 writes)
    float gi = (float)pv.h[0] + g4[0];
    float gf = (float)pv.h[1] + g4[1];
    float gg = (float)pv.h[2] + g4[2];
    float go = (float)pv.h[3] + g4[3];
    cc = sigm(gf)*cc + sigm(gi)*ftanh(gg);
    float h = sigm(go)*ftanh(cc);
    if (hi == 0) {
      hb[cur^1][e] = (h16)h;
      hout[(size_t)t*512 + half + e] = h;
      if (isNote) out_noteh[(size_t)t*512 + half + e] = h;
    }
    cur ^= 1;
    __syncthreads();   // new h visible; ping-pong makes one barrier safe
  }
}

// ---------------- K3: beat segment attention ------------------------------
__global__ __launch_bounds__(256) void k3_battn(
    const float* __restrict__ note_h,
    const float* __restrict__ Wba, const float* __restrict__ bba,
    float* __restrict__ beat_nodes)
{
  const int b = blockIdx.x;
  const int tid = threadIdx.x;
  __shared__ float nh[8][512];
  for (int i = tid; i < 8*512; i += 256)
    nh[i>>9][i&511] = note_h[(size_t)b*8*512 + i];
  __syncthreads();
  for (int dc = 0; dc < 2; ++dc) {
    int d = dc*256 + tid;
    const float* wr = Wba + (size_t)d*512;
    float bb = bba[d];
    float l[8];
#pragma unroll
    for (int n=0;n<8;++n) l[n]=bb;
#pragma unroll 4
    for (int j=0; j<512; ++j) {
      float w = wr[j];
#pragma unroll
      for (int n=0;n<8;++n) l[n] += w*nh[n][j];
    }
    float m = l[0];
#pragma unroll
    for (int n=1;n<8;++n) m = fmaxf(m, l[n]);
    float s = 0.f, o = 0.f;
#pragma unroll
    for (int n=0;n<8;++n) { float e = __expf(l[n]-m); s += e; o += e*nh[n][d]; }
    beat_nodes[(size_t)b*512 + d] = o / s;
  }
}

// ---------------- K4: beat input gates ------------------------------------
__global__ __launch_bounds__(256) void k4_bgates(
    const float* __restrict__ beat_nodes,
    const float* __restrict__ beatWi, const float* __restrict__ beatB,
    float* __restrict__ preB)
{
  const int dir = blockIdx.y, b0 = blockIdx.x*8, tid = threadIdx.x;
  __shared__ float nd[8][512];
  for (int i = tid; i < 8*512; i += 256)
    nd[i>>9][i&511] = beat_nodes[(size_t)b0*512 + i];
  __syncthreads();
  for (int gc = 0; gc < 2; ++gc) {
    int g = gc*256 + tid;
    const float* wr = beatWi + ((size_t)dir*512 + g)*512;
    float bias = beatB[dir*512 + g];
    float acc[8];
#pragma unroll
    for (int n=0;n<8;++n) acc[n]=bias;
#pragma unroll 4
    for (int j=0; j<512; ++j) {
      float w = wr[j];
#pragma unroll
      for (int n=0;n<8;++n) acc[n] += w*nd[n][j];
    }
#pragma unroll
    for (int n=0;n<8;++n)
      preB[((size_t)dir*512 + (b0+n))*512 + g] = acc[n];
  }
}

// ---------------- K5: beat recurrence (H=128, weights in regs) ------------
__global__ __launch_bounds__(512) void k5_brec(
    const float* __restrict__ beatWh,
    const float* __restrict__ preB,
    float* __restrict__ beat_h)
{
  const int dir = blockIdx.x, L = threadIdx.x;
  h16x2 w[64];
  {
    const float2* p = (const float2*)(beatWh + ((size_t)dir*512 + L)*128);
#pragma unroll
    for (int c=0;c<64;++c){
      float2 v = p[c];
      w[c] = f2h2(v.x, v.y);
    }
  }
#pragma unroll
  for (int c=0;c<64;++c) pinv(w[c]);
  __shared__ __align__(16) h16 hb[128];
  __shared__ float gl[512];
  if (L < 128) hb[L] = (h16)0.f;
  float cc = 0.f;
  __syncthreads();
  const bool fwd = (dir == 0);
  for (int it = 0; it < 512; ++it) {
    const int t = fwd ? it : 511 - it;
    float pr = preB[((size_t)dir*512 + t)*512 + L];
    float ac[4] = {0.f,0.f,0.f,0.f};
#pragma unroll
    for (int c=0;c<16;++c){
      U4 hh; hh.u = *(const uint4*)&hb[c*8];
#pragma unroll
      for (int i=0;i<4;++i) ac[i] = fdot2(w[c*4+i], hh.p[i], ac[i]);
    }
    gl[L] = pr + ((ac[0]+ac[1]) + (ac[2]+ac[3]));
    __syncthreads();
    if (L < 128) {
      float gi = gl[L], gf = gl[L+128], gg = gl[L+256], go = gl[L+384];
      cc = sigm(gf)*cc + sigm(gi)*ftanh(gg);
      float h = sigm(go)*ftanh(cc);
      hb[L] = (h16)h;
      beat_h[(size_t)t*256 + dir*128 + L] = h;
    }
    __syncthreads();
  }
}

// ---------------- K6: measure segment attention ---------------------------
__global__ __launch_bounds__(256) void k6_mattn(
    const float* __restrict__ beat_h,
    const float* __restrict__ Wma, const float* __restrict__ bma,
    float* __restrict__ meas_nodes)
{
  const int m = blockIdx.x, tid = threadIdx.x;
  __shared__ float bh[4][256];
  for (int i = tid; i < 4*256; i += 256)
    bh[i>>8][i&255] = beat_h[(size_t)m*4*256 + i];
  __syncthreads();
  int d = tid;
  const float* wr = Wma + (size_t)d*256;
  float bb = bma[d];
  float l[4];
#pragma unroll
  for (int n=0;n<4;++n) l[n]=bb;
#pragma unroll 4
  for (int j=0; j<256; ++j) {
    float w = wr[j];
#pragma unroll
    for (int n=0;n<4;++n) l[n] += w*bh[n][j];
  }
  float mm = fmaxf(fmaxf(l[0],l[1]), fmaxf(l[2],l[3]));
  float s = 0.f, o = 0.f;
#pragma unroll
  for (int n=0;n<4;++n) { float e = __expf(l[n]-mm); s += e; o += e*bh[n][d]; }
  meas_nodes[(size_t)m*256 + d] = o / s;
}

// ---------------- K7: measure input gates ---------------------------------
__global__ __launch_bounds__(256) void k7_mgates(
    const float* __restrict__ meas_nodes,
    const float* __restrict__ measWi, const float* __restrict__ measB,
    float* __restrict__ preM)
{
  const int dir = blockIdx.y, m0 = blockIdx.x*8, tid = threadIdx.x;
  __shared__ float nd[8][256];
  for (int i = tid; i < 8*256; i += 256)
    nd[i>>8][i&255] = meas_nodes[(size_t)m0*256 + i];
  __syncthreads();
  int g = tid;
  const float* wr = measWi + ((size_t)dir*256 + g)*256;
  float bias = measB[dir*256 + g];
  float acc[8];
#pragma unroll
  for (int n=0;n<8;++n) acc[n]=bias;
#pragma unroll 4
  for (int j=0; j<256; ++j) {
    float w = wr[j];
#pragma unroll
    for (int n=0;n<8;++n) acc[n] += w*nd[n][j];
  }
#pragma unroll
  for (int n=0;n<8;++n)
    preM[((size_t)dir*128 + (m0+n))*256 + g] = acc[n];
}

// ---------------- K8: measure recurrence (H=64) ---------------------------
__global__ __launch_bounds__(256, 2) void k8_mrec(
    const float* __restrict__ measWh,
    const float* __restrict__ preM,
    float* __restrict__ meas_h)
{
  const int dir = blockIdx.x, L = threadIdx.x;
  h16x2 w[32];
  {
    const float2* p = (const float2*)(measWh + ((size_t)dir*256 + L)*64);
#pragma unroll
    for (int c=0;c<32;++c){
      float2 v = p[c];
      w[c] = f2h2(v.x, v.y);
    }
  }
#pragma unroll
  for (int c=0;c<32;++c) pinv(w[c]);
  __shared__ __align__(16) h16 hb[64];
  __shared__ float gl[256];
  if (L < 64) hb[L] = (h16)0.f;
  float cc = 0.f;
  __syncthreads();
  const bool fwd = (dir == 0);
  for (int it = 0; it < 128; ++it) {
    const int t = fwd ? it : 127 - it;
    float pr = preM[((size_t)dir*128 + t)*256 + L];
    float ac[4] = {0.f,0.f,0.f,0.f};
#pragma unroll
    for (int c=0;c<8;++c){
      U4 hh; hh.u = *(const uint4*)&hb[c*8];
#pragma unroll
      for (int i=0;i<4;++i) ac[i] = fdot2(w[c*4+i], hh.p[i], ac[i]);
    }
    gl[L] = pr + ((ac[0]+ac[1]) + (ac[2]+ac[3]));
    __syncthreads();
    if (L < 64) {
      float gi = gl[L], gf = gl[L+64], gg = gl[L+128], go = gl[L+192];
      cc = sigm(gf)*cc + sigm(gi)*ftanh(gg);
      float h = sigm(go)*ftanh(cc);
      hb[L] = (h16)h;
      meas_h[(size_t)t*128 + dir*64 + L] = h;
    }
    __syncthreads();
  }
}

// ---------------- K9: scan known-part GEMM (pre_out + pre_fc) -------------
__global__ __launch_bounds__(256) void k9_scanpre(
    const float* __restrict__ note_h, const float* __restrict__ voice_h,
    const float* __restrict__ beat_h, const float* __restrict__ meas_h,
    const float* __restrict__ xf,
    const h16* __restrict__ outWiF, const h16* __restrict__ WfcKF,
    const float* __restrict__ outB, const float* __restrict__ bfc,
    float* __restrict__ pre_out, float* __restrict__ pre_fc)
{
  const int t0 = blockIdx.x*8, tid = threadIdx.x;
  __shared__ __align__(16) h16 kn[8][1416];
  const float qpm = xf[5], tp0 = xf[76], tp1 = xf[77];
  for (int i = tid; i < 8*1416; i += 256) {
    int tt = i/1416, c = i - tt*1416;
    int t = t0 + tt;
    float v;
    if (c < 512) v = note_h[(size_t)t*512 + c];
    else if (c < 768) v = beat_h[(size_t)(t>>3)*256 + (c-512)];
    else if (c < 896) v = meas_h[(size_t)(t>>5)*128 + (c-768)];
    else if (c < 1408) v = voice_h[(size_t)t*512 + (c-896)];
    else if (c == 1408) v = qpm;
    else if (c == 1409) v = tp0;
    else if (c == 1410) v = tp1;
    else v = 0.f;
    kn[tt][c] = (h16)v;
  }
  __syncthreads();
  for (int rr = 0; rr < 3; ++rr) {
    int r = (rr < 2) ? (tid + rr*256) : (512 + tid);
    if (rr == 2 && tid >= 10) break;
    const h16* wrow = (r < 512) ? (outWiF + (size_t)r*1416) : (WfcKF + (size_t)(r-512)*1416);
    float bias = (r < 512) ? outB[r] : bfc[r-512];
    float acc[8];
#pragma unroll
    for (int tt=0;tt<8;++tt) acc[tt] = bias;
    for (int cu = 0; cu < 177; ++cu) {
      U4 wv; wv.u = *(const uint4*)(wrow + cu*8);
#pragma unroll
      for (int tt=0; tt<8; ++tt) {
        U4 kv; kv.u = *(const uint4*)&kn[tt][cu*8];
#pragma unroll
        for (int i=0;i<4;++i) acc[tt] = fdot2(wv.p[i], kv.p[i], acc[tt]);
      }
    }
#pragma unroll
    for (int tt=0; tt<8; ++tt) {
      if (r < 512) pre_out[(size_t)(t0+tt)*512 + r] = acc[tt];
      else pre_fc[(size_t)(t0+tt)*16 + (r-512)] = acc[tt];
    }
  }
}

// ---------------- K9b: bt-LSTM known-part gates ---------------------------
__global__ __launch_bounds__(256) void k9b_btpre(
    const float* __restrict__ beat_h, const float* __restrict__ xf,
    const float* __restrict__ btWi, const float* __restrict__ btB,
    float* __restrict__ pre_bt)
{
  const int b0 = blockIdx.x*8, tid = threadIdx.x;
  __shared__ float bh[8][256];
  __shared__ float btv[8][3];
  for (int i = tid; i < 8*256; i += 256)
    bh[i>>8][i&255] = beat_h[(size_t)b0*256 + i];
  if (tid < 24) {
    int n = tid/3, j = tid - n*3;
    btv[n][j] = xf[(size_t)(b0+n)*8*78 + 28 + j];
  }
  __syncthreads();
  const float qpm = xf[5], tp0 = xf[76], tp1 = xf[77];
  for (int gc = 0; gc < 2; ++gc) {
    int g = gc*256 + tid;
    const float* row = btWi + (size_t)g*273;
    float bias = btB[g];
    float acc[8];
#pragma unroll
    for (int n=0;n<8;++n) acc[n]=bias;
#pragma unroll 4
    for (int j = 0; j < 256; ++j) {
      float w = row[j];
#pragma unroll
      for (int n=0;n<8;++n) acc[n] += w*bh[n][j];
    }
    float w257 = row[257], w258 = row[258], w259 = row[259];
    float w260 = row[260], w261 = row[261], w262 = row[262];
#pragma unroll
    for (int n=0;n<8;++n) {
      acc[n] += w257*qpm + w258*tp0 + w259*tp1
              + w260*btv[n][0] + w261*btv[n][1] + w262*btv[n][2];
      pre_bt[(size_t)(b0+n)*512 + g] = acc[n];
    }
  }
}

// ---------------- K10: the grand sequential scan --------------------------
// v2: (a) waves_per_eu(2,2) so owh/btw stay in ARCH VGPRs (no acc parking);
// (b) the 64-fdot2 recurrent dot for step t+1 runs in the D/E phase
// (overlapped with wave0's epilogue; depends only on oh16 written in B(t));
// loop-top only finishes gl = prv + acA + oseq*pofc; (c) pointer-increment
// prefetch, guard-free (over-reads land in adjacent workspace regions);
// (d) pofc read as float4s.
__global__ __launch_bounds__(512) __attribute__((amdgpu_waves_per_eu(2, 2)))
void k10_scan(
    const float* __restrict__ pre_out, const float* __restrict__ pre_fc,
    const float* __restrict__ pre_bt,
    const float* __restrict__ outWh, const float* __restrict__ btWh,
    const float* __restrict__ outWi, const float* __restrict__ btWi,
    const float* __restrict__ Wfc,
    const float* __restrict__ Wta, const float* __restrict__ bta,
    const float* __restrict__ Wt1, const float* __restrict__ bt1,
    const float* __restrict__ Wt2, const float* __restrict__ bt2,
    const float* __restrict__ yf,
    float* __restrict__ out)
{
  const int L = threadIdx.x;
  h16x2 owh[64], btw[64];
  {
    const float2* p = (const float2*)(outWh + (size_t)L*128);
    const float2* q = (const float2*)(btWh + (size_t)L*128);
#pragma unroll
    for (int c=0;c<64;++c){
      float2 a = p[c]; owh[c] = f2h2(a.x, a.y);
      float2 b = q[c]; btw[c] = f2h2(b.x, b.y);
    }
  }
#pragma unroll
  for (int c=0;c<64;++c){ pinv(owh[c]); pinv(btw[c]); }
  float oseq[13];
#pragma unroll
  for (int j=0;j<13;++j) oseq[j] = outWi[(size_t)L*1424 + 1408 + j];
  float btpt = btWi[(size_t)L*273 + 256];
  float btrn[10];
#pragma unroll
  for (int d=0;d<10;++d) btrn[d] = btWi[(size_t)L*273 + 263 + d];

  __shared__ __align__(16) h16 oh16[128];
  __shared__ __align__(16) h16 th16[128];
  __shared__ __align__(16) h16 Wt1f[128*136];  // f16, padded row stride 136
  __shared__ __align__(16) h16 WfcD[10*128];
  __shared__ float gl[512], gb[512];
  __shared__ __align__(16) float pofc[16];
  __shared__ float ptvS;
  __shared__ float buf[8][10];
  __shared__ float rn[10], att[8][10], r1v[128], ytail[10];
  __shared__ float WfcSeq[10][13];
  __shared__ float WtaS[100], btaS[10], Wt2S[128], bt1S[128], bt2S;

  for (int i=L; i<128*128; i+=512) Wt1f[(i>>7)*136 + (i&127)] = (h16)Wt1[i];
  for (int i=L; i<10*128; i+=512)  WfcD[i] = (h16)Wfc[(size_t)(i>>7)*1552 + (i&127)];
  if (L < 100) WtaS[L] = Wta[L];
  if (L < 10)  btaS[L] = bta[L];
  if (L < 128) { Wt2S[L] = Wt2[L]; bt1S[L] = bt1[L]; }
  if (L == 0)  bt2S = bt2[0];
  if (L < 128) { oh16[L] = (h16)0.f; th16[L] = (h16)0.f; }
  if (L < 11) pofc[L] = yf[L];
  if (L >= 11 && L < 16) pofc[L] = 0.f;
  if (L == 0) ptvS = yf[0];
  if (L < 10) ytail[L] = yf[1+L];
  if (L < 80) buf[L/10][L%10] = 0.f;
  if (L < 130) WfcSeq[L/13][L%13] = Wfc[(size_t)(L/13)*1552 + 1536 + (L%13)];
  float oc = 0.f, tc = 0.f;
  const int dD = L >> 2, qD = L & 3;
  float prv  = pre_out[L];                       // prefetched pre_out row t=0
  float prbt = pre_bt[L];                        // prefetched beat 0
  float prfc = (L < 40 && qD == 0) ? pre_fc[dD] : 0.f;
  const float* pp_out = pre_out + 512 + L;
  const float* pp_bt  = pre_bt  + 512 + L;
  const float* pp_fc  = pre_fc  + 16 + dD;
  float acA = 0.f, acB = 0.f;   // pipelined recurrent dots (oh16/th16 = 0)
  __syncthreads();

  for (int t = 0; t < NT; ++t) {
    const bool isb = (t & 7) == 0;
    if (isb) {
      if (t == 0) {
        if (L < 10) rn[L] = ytail[L];
      } else {
        if (L < 80) {
          int n = L/10, d = L - n*10;
          float s = btaS[d];
#pragma unroll
          for (int j=0;j<10;++j) s += buf[n][j]*WtaS[d*10 + j];
          att[n][d] = s;
        }
        __syncthreads();
        if (L < 10) {
          float m = att[0][L];
#pragma unroll
          for (int n=1;n<8;++n) m = fmaxf(m, att[n][L]);
          float s = 0.f, acc = 0.f;
#pragma unroll
          for (int n=0;n<8;++n) { float e = __expf(att[n][L]-m); s += e; acc += e*buf[n][L]; }
          rn[L] = acc/s;
        }
      }
      __syncthreads();
    }
    // A-tail: finish gates for t (dot already in acA/acB from prev iter)
    {
      float4 p0 = *(const float4*)&pofc[0];
      float4 p1 = *(const float4*)&pofc[4];
      float4 p2 = *(const float4*)&pofc[8];
      float  pc = pofc[12];
      float a = prv + acA;
      a += oseq[0]*p0.x + oseq[1]*p0.y + oseq[2]*p0.z + oseq[3]*p0.w;
      a += oseq[4]*p1.x + oseq[5]*p1.y + oseq[6]*p1.z + oseq[7]*p1.w;
      a += oseq[8]*p2.x + oseq[9]*p2.y + oseq[10]*p2.z + oseq[11]*p2.w;
      a += oseq[12]*pc;
      gl[L] = a;
      prv = *pp_out; pp_out += 512;        // safe over-read at t=NT-1
    }
    if (isb) {
      float b = prbt + btpt*ptvS + acB;
#pragma unroll
      for (int d=0;d<10;++d) b += btrn[d]*rn[d];
      gb[L] = b;
      prbt = *pp_bt; pp_bt += 512;         // safe over-read at last beat
    }
    __syncthreads();                       // s1
    // B: cells
    if (L < 128) {
      float gi = gl[L], gf = gl[L+128], gg = gl[L+256], go = gl[L+384];
      oc = sigm(gf)*oc + sigm(gi)*ftanh(gg);
      float nh = sigm(go)*ftanh(oc);
      oh16[L] = (h16)nh;
    } else if (L < 256 && isb) {
      int j = L - 128;
      float gi = gb[j], gf = gb[j+128], gg = gb[j+256], go = gb[j+384];
      tc = sigm(gf)*tc + sigm(gi)*ftanh(gg);
      float nth = sigm(go)*ftanh(tc);
      th16[j] = (h16)nth;
    }
    __syncthreads();                       // s2
    // C1: tempo hidden layer (beat steps; Wt1 f16 in LDS, th16 = f16 nth)
    if (isb) {
      if (L < 128) {
        float ac[4] = {0.f,0.f,0.f,0.f};
        const h16* wrow = &Wt1f[L*136];
#pragma unroll
        for (int k=0;k<16;++k){
          U4 wv; wv.u = *(const uint4*)(wrow + k*8);
          U4 hh; hh.u = *(const uint4*)&th16[k*8];
#pragma unroll
          for (int i=0;i<4;++i) ac[i] = fdot2(wv.p[i], hh.p[i], ac[i]);
        }
        float s = bt1S[L] + ((ac[0]+ac[1]) + (ac[2]+ac[3]));
        r1v[L] = fmaxf(s, 0.f);
      }
      __syncthreads();
    }
    // wave 0: C2 (ptv) + D (out_fc) + E (epilogue) — runs overlapped with
    // the early recurrent dot for t+1 done by all waves below.
    if (L < 64) {
      float ptv_l;
      if (isb) {
        float p = Wt2S[L]*r1v[L] + Wt2S[L+64]*r1v[L+64];
#pragma unroll
        for (int sft=32; sft>0; sft>>=1) p += __shfl_xor(p, sft, 64);
        ptv_l = p + bt2S;
        if (L == 0) ptvS = ptv_l;
      } else {
        ptv_l = ptvS;
      }
      // D
      float s = 0.f;
      if (L < 40) {
        const h16* wr = &WfcD[dD*128 + qD*32];
#pragma unroll
        for (int j=0;j<32;++j) s += (float)wr[j] * (float)oh16[qD*32 + j];
      }
      s += __shfl_xor(s, 1, 64);
      s += __shfl_xor(s, 2, 64);
      float e = 0.f;
      if (L < 40 && qD == 0) {
        e = prfc;
#pragma unroll
        for (int j=0;j<13;++j) e += WfcSeq[dD][j]*pofc[j];
        prfc = *pp_fc; pp_fc += 16;        // safe over-read at t=NT-1
      }
      float ofc = s + e;                   // final at lanes 4d, d<10
      // E
      int srcE = (L >= 1 && L < 11) ? 4*(L-1) : ((L >= 11 && L < 13) ? 4*(L-11) : 0);
      float valE = __shfl(ofc, srcE, 64);
      float bval = __shfl(ofc, 4*(L & 15), 64);
      if (L == 0)      { out[(size_t)t*11] = ptv_l; pofc[0] = ptv_l; }
      else if (L < 11) { out[(size_t)t*11 + L] = valE; pofc[L] = valE; }
      else if (L < 13) { pofc[L] = valE; }
      if (L < 10) buf[t & 7][L] = bval;
    }
    // early recurrent dot for step t+1 (all threads; depends only on oh16)
    {
      float a0=0.f,a1=0.f,a2=0.f,a3=0.f;
#pragma unroll
      for (int c=0;c<16;++c){
        U4 hh; hh.u = *(const uint4*)&oh16[c*8];
        a0 = fdot2(owh[c*4+0], hh.p[0], a0);
        a1 = fdot2(owh[c*4+1], hh.p[1], a1);
        a2 = fdot2(owh[c*4+2], hh.p[2], a2);
        a3 = fdot2(owh[c*4+3], hh.p[3], a3);
      }
      acA = (a0+a1) + (a2+a3);
    }
    if (((t+1) & 7) == 0) {                // th16 unchanged since B(t-7)
      float b0=0.f,b1=0.f,b2=0.f,b3=0.f;
#pragma unroll
      for (int c=0;c<16;++c){
        U4 hh; hh.u = *(const uint4*)&th16[c*8];
        b0 = fdot2(btw[c*4+0], hh.p[0], b0);
        b1 = fdot2(btw[c*4+1], hh.p[1], b1);
        b2 = fdot2(btw[c*4+2], hh.p[2], b2);
        b3 = fdot2(btw[c*4+3], hh.p[3], b3);
      }
      acB = (b0+b1) + (b2+b3);
    }
    __syncthreads();                       // s3
  }
}

// ---------------- launcher ------------------------------------------------
extern "C" void kernel_launch(void* const* d_in, const int* in_sizes, int n_in,
                              void* d_out, int out_size, void* d_ws, size_t ws_size,
                              hipStream_t stream)
{
  const float* x      = (const float*)d_in[0];
  const float* y      = (const float*)d_in[1];
  const float* noteWi = (const float*)d_in[4];
  const float* noteWh = (const float*)d_in[5];
  const float* noteB  = (const float*)d_in[6];
  const float* voiceWi= (const float*)d_in[7];
  const float* voiceWh= (const float*)d_in[8];
  const float* voiceB = (const float*)d_in[9];
  const float* beatWi = (const float*)d_in[10];
  const float* beatWh = (const float*)d_in[11];
  const float* beatB  = (const float*)d_in[12];
  const float* measWi = (const float*)d_in[13];
  const float* measWh = (const float*)d_in[14];
  const float* measB  = (const float*)d_in[15];
  const float* Wba    = (const float*)d_in[16];
  const float* bba    = (const float*)d_in[17];
  const float* Wma    = (const float*)d_in[18];
  const float* bma    = (const float*)d_in[19];
  const float* Wta    = (const float*)d_in[20];
  const float* bta    = (const float*)d_in[21];
  const float* outWi  = (const float*)d_in[22];
  const float* outWh  = (const float*)d_in[23];
  const float* outB   = (const float*)d_in[24];
  const float* Wfc    = (const float*)d_in[25];
  const float* bfc    = (const float*)d_in[26];
  const float* btWi   = (const float*)d_in[27];
  const float* btWh   = (const float*)d_in[28];
  const float* btB    = (const float*)d_in[29];
  const float* Wt1    = (const float*)d_in[30];
  const float* bt1    = (const float*)d_in[31];
  const float* Wt2    = (const float*)d_in[32];
  const float* bt2    = (const float*)d_in[33];

  float* fws = (float*)d_ws;
  float* note_h     = fws + 0;
  float* voice_h    = fws + 2097152;
  float* beat_nodes = fws + 4194304;
  float* preB       = fws + 4456448;
  float* beat_h     = fws + 4980736;
  float* meas_nodes = fws + 5111808;
  float* preM       = fws + 5144576;
  float* meas_h     = fws + 5210112;
  float* pre_out    = fws + 5226496;
  float* pre_fc     = fws + 7323648;
  float* pre_bt     = fws + 7389184;
  h16* hws   = (h16*)(fws + 7651328);
  h16* preNV  = hws;
  h16* WhF    = hws + 16777216;
  h16* outWiF = hws + 17825792;
  h16* WfcKF  = hws + 18550784;

  float* out_outs  = (float*)d_out;
  float* out_noteh = out_outs + OUTS_OFF;

  hipLaunchKernelGGL(k0_prep, dim3(1024), dim3(256), 0, stream,
                     noteWh, voiceWh, outWi, Wfc, WhF, outWiF, WfcKF);
  hipLaunchKernelGGL(k1_xgates, dim3(256,4), dim3(256), 0, stream,
                     x, noteWi, noteB, voiceWi, voiceB, preNV);
  hipLaunchKernelGGL(k2_nvrec, dim3(4), dim3(512), 0, stream,
                     WhF, preNV, note_h, voice_h, out_noteh);
  hipLaunchKernelGGL(k3_battn, dim3(512), dim3(256), 0, stream,
                     note_h, Wba, bba, beat_nodes);
  hipLaunchKernelGGL(k4_bgates, dim3(64,2), dim3(256), 0, stream,
                     beat_nodes, beatWi, beatB, preB);
  hipLaunchKernelGGL(k5_brec, dim3(2), dim3(512), 0, stream,
                     beatWh, preB, beat_h);
  hipLaunchKernelGGL(k6_mattn, dim3(128), dim3(256), 0, stream,
                     beat_h, Wma, bma, meas_nodes);
  hipLaunchKernelGGL(k7_mgates, dim3(16,2), dim3(256), 0, stream,
                     meas_nodes, measWi, measB, preM);
  hipLaunchKernelGGL(k8_mrec, dim3(2), dim3(256), 0, stream,
                     measWh, preM, meas_h);
  hipLaunchKernelGGL(k9b_btpre, dim3(64), dim3(256), 0, stream,
                     beat_h, x, btWi, btB, pre_bt);
  hipLaunchKernelGGL(k9_scanpre, dim3(512), dim3(256), 0, stream,
                     note_h, voice_h, beat_h, meas_h, x, outWiF, WfcKF, outB, bfc, pre_out, pre_fc);
  hipLaunchKernelGGL(k10_scan, dim3(1), dim3(512), 0, stream,
                     pre_out, pre_fc, pre_bt, outWh, btWh, outWi, btWi, Wfc,
                     Wta, bta, Wt1, bt1, Wt2, bt2, y, out_outs);
}

// Round 5
// 14025.523 us; speedup vs baseline: 1.4133x; 1.0330x over previous
//
#include <hip/hip_runtime.h>
#include <hip/hip_bf16.h>

typedef unsigned int u32;
typedef _Float16 h16;
typedef __attribute__((ext_vector_type(2))) _Float16 h16x2;

union U4 { uint4 u; h16x2 p[4]; };

static __device__ __forceinline__ float sigm(float x){ return 1.0f / (1.0f + __expf(-x)); }
static __device__ __forceinline__ float ftanh(float x){ return 1.0f - 2.0f/(1.0f + __expf(2.0f*x)); }
static __device__ __forceinline__ h16x2 f2h2(float a, float b){
  h16x2 r; r[0] = (h16)a; r[1] = (h16)b; return r;
}
// Pin a packed-f16 pair into an arch-VGPR (defeats AGPR-parking / remat).
static __device__ __forceinline__ void pinv(h16x2 &x){
  u32 t = __builtin_bit_cast(u32, x);
  asm volatile("" : "+v"(t));
  x = __builtin_bit_cast(h16x2, t);
}

#if defined(__has_builtin)
#if __has_builtin(__builtin_amdgcn_fdot2)
#define FDOT2_NATIVE 1
#endif
#endif
static __device__ __forceinline__ float fdot2(h16x2 a, h16x2 b, float c){
#ifdef FDOT2_NATIVE
  return __builtin_amdgcn_fdot2(a, b, c, false);
#else
  return c + (float)a[0]*(float)b[0] + (float)a[1]*(float)b[1];
#endif
}

#define NT 4096
#define OUTS_OFF 45056

// ---------------- K0: weight conversions (f32 -> f16, packed layouts) ----
__global__ __launch_bounds__(256) void k0_prep(
    const float* __restrict__ noteWh, const float* __restrict__ voiceWh,
    const float* __restrict__ outWi,  const float* __restrict__ Wfc,
    h16* __restrict__ WhF, h16* __restrict__ outWiF, h16* __restrict__ WfcKF)
{
  const int NWH = 4*1024*256;     // 1048576
  const int NOW = 512*1416;       // 724992
  const int NFC = 10*1416;        // 14160
  for (int i = blockIdx.x*256 + threadIdx.x; i < NWH + NOW + NFC; i += gridDim.x*256) {
    if (i < NWH) {
      int dir = i >> 18;
      int rem = i & 262143;
      const float* src = (dir < 2) ? noteWh : voiceWh;
      WhF[i] = (h16)src[((dir & 1) << 18) + rem];
    } else if (i < NWH + NOW) {
      int j = i - NWH;
      int r = j / 1416, c = j - r*1416;
      float v = 0.f;
      if (c < 1408) v = outWi[(size_t)r*1424 + c];
      else if (c < 1411) v = outWi[(size_t)r*1424 + 1421 + (c-1408)];
      outWiF[j] = (h16)v;
    } else {
      int j = i - NWH - NOW;
      int r = j / 1416, c = j - r*1416;
      float v = 0.f;
      if (c < 1408) v = Wfc[(size_t)r*1552 + 128 + c];
      else if (c < 1411) v = Wfc[(size_t)r*1552 + 1549 + (c-1408)];
      WfcKF[j] = (h16)v;
    }
  }
}

// ---------------- K1: note/voice input gates: pre = b + Wi @ x ------------
// preNV layout: [dir][t][e*4 + gate]  (gate-interleaved so K2 loads one u2)
__global__ __launch_bounds__(256) void k1_xgates(
    const float* __restrict__ x,
    const float* __restrict__ noteWi, const float* __restrict__ noteB,
    const float* __restrict__ voiceWi, const float* __restrict__ voiceB,
    h16* __restrict__ preNV)
{
  const int dir = blockIdx.y;
  const int t0  = blockIdx.x * 16;
  const int tid = threadIdx.x;
  __shared__ float xs[16][80];
  for (int i = tid; i < 16*78; i += 256) {
    int tt = i / 78, j = i - tt*78;
    xs[tt][j] = x[(size_t)(t0+tt)*78 + j];
  }
  __syncthreads();
  const float* Wi = (dir < 2) ? noteWi : voiceWi;
  const float* B  = (dir < 2) ? noteB  : voiceB;
  const int dw = dir & 1;
  for (int gc = 0; gc < 4; ++gc) {
    int g = gc*256 + tid;
    const float* row = Wi + ((size_t)dw*1024 + g)*78;
    float bias = B[dw*1024 + g];
    float acc[16];
#pragma unroll
    for (int tt=0; tt<16; ++tt) acc[tt] = bias;
#pragma unroll 6
    for (int j=0; j<78; ++j) {
      float w = row[j];
#pragma unroll
      for (int tt=0; tt<16; ++tt)
        acc[tt] += w*xs[tt][j];
    }
#pragma unroll
    for (int tt=0; tt<16; ++tt)
      preNV[((size_t)dir*NT + (t0+tt))*1024 + (tid*4 + gc)] = (h16)acc[tt];
  }
}

// ---------------- K2: note/voice recurrences (4 dirs, 1 block each) -------
// Round-2/4 proven structure (6.87 ms measured): unchanged this round.
__global__ __launch_bounds__(512) __attribute__((amdgpu_waves_per_eu(2, 2)))
void k2_nvrec(
    const h16* __restrict__ WhF,
    const h16* __restrict__ preNV,
    float* __restrict__ note_h,
    float* __restrict__ voice_h,
    float* __restrict__ out_noteh)
{
  const int dir = blockIdx.x;
  const int L = threadIdx.x;
  const int lane = L & 63;
  const int wid  = L >> 6;           // 0..7
  const int hi   = lane >> 5;        // column half
  const int e    = wid*32 + (lane & 31);   // element 0..255
  const int c0   = hi*128;
  const h16* Wb = WhF + (size_t)dir*1024*256;

  // Register weights: cols c0..c0+95, gates 0..3 (i,f,g,o)
  h16x2 w[4][48];
#pragma unroll
  for (int g=0; g<4; ++g) {
    const h16* row = Wb + (size_t)(g*256 + e)*256 + c0;
#pragma unroll
    for (int cb=0; cb<12; ++cb) {
      U4 a; a.u = *(const uint4*)(row + cb*8);
#pragma unroll
      for (int i=0;i<4;++i) w[g][cb*4+i] = a.p[i];
    }
  }
#pragma unroll
  for (int g=0; g<4; ++g)
#pragma unroll
    for (int c=0;c<48;++c) pinv(w[g][c]);

  // LDS weights: cols c0+96..c0+127, lane-dense: [(cb*4+g)*2+hi][e][8]
  __shared__ __align__(16) h16 Wl[4*4*2*256*8];   // 128 KiB
  __shared__ __align__(16) h16 hb[2][256];
#pragma unroll
  for (int cb=0; cb<4; ++cb)
#pragma unroll
    for (int g=0; g<4; ++g) {
      const h16* src = Wb + (size_t)(g*256 + e)*256 + c0 + 96 + cb*8;
      *(uint4*)&Wl[(size_t)((((cb*4+g)*2 + hi)*256 + e))*8] = *(const uint4*)src;
    }
  if (hi == 0) hb[0][e] = (h16)0.f;
  float cc = 0.f;
  __syncthreads();

  const bool fwd = ((dir & 1) == 0);
  const bool isNote = (dir < 2);
  float* hout = isNote ? note_h : voice_h;
  const int half = (dir & 1) * 256;
  const h16* pre = preNV + (size_t)dir*NT*1024;
  int cur = 0;
  const int step = fwd ? 1 : -1;
  int t = fwd ? 0 : NT-1;

  union PU { uint2 u; h16 h[4]; };
  PU pv_n; pv_n.u = *(const uint2*)(pre + (size_t)t*1024 + e*4);

  for (int it = 0; it < NT; ++it, t += step) {
    PU pv = pv_n;
    if (it+1 < NT) pv_n.u = *(const uint2*)(pre + (size_t)(t+step)*1024 + e*4);

    float ac[4][2] = {{0.f,0.f},{0.f,0.f},{0.f,0.f},{0.f,0.f}};
    // register-resident columns
#pragma unroll
    for (int cb=0; cb<12; ++cb) {
      U4 hh; hh.u = *(const uint4*)&hb[cur][c0 + cb*8];
#pragma unroll
      for (int i=0;i<4;++i) {
        ac[0][i&1] = fdot2(w[0][cb*4+i], hh.p[i], ac[0][i&1]);
        ac[1][i&1] = fdot2(w[1][cb*4+i], hh.p[i], ac[1][i&1]);
        ac[2][i&1] = fdot2(w[2][cb*4+i], hh.p[i], ac[2][i&1]);
        ac[3][i&1] = fdot2(w[3][cb*4+i], hh.p[i], ac[3][i&1]);
      }
    }
    // LDS-resident columns
#pragma unroll
    for (int cb=0; cb<4; ++cb) {
      U4 hh; hh.u = *(const uint4*)&hb[cur][c0 + 96 + cb*8];
#pragma unroll
      for (int g=0; g<4; ++g) {
        U4 wv; wv.u = *(const uint4*)&Wl[(size_t)((((cb*4+g)*2 + hi)*256 + e))*8];
#pragma unroll
        for (int i=0;i<4;++i) ac[g][i&1] = fdot2(wv.p[i], hh.p[i], ac[g][i&1]);
      }
    }
    // combine halves within the wave (lane ^ 32)
    float g4[4];
#pragma unroll
    for (int g=0; g<4; ++g) {
      float s = ac[g][0] + ac[g][1];
      s += __shfl_xor(s, 32, 64);
      g4[g] = s;
    }
    // cell (both halves compute identically; hi==0 writes)
    float gi = (float)pv.h[0] + g4[0];
    float gf = (float)pv.h[1] + g4[1];
    float gg = (float)pv.h[2] + g4[2];
    float go = (float)pv.h[3] + g4[3];
    cc = sigm(gf)*cc + sigm(gi)*ftanh(gg);
    float h = sigm(go)*ftanh(cc);
    if (hi == 0) {
      hb[cur^1][e] = (h16)h;
      hout[(size_t)t*512 + half + e] = h;
      if (isNote) out_noteh[(size_t)t*512 + half + e] = h;
    }
    cur ^= 1;
    __syncthreads();   // new h visible; ping-pong makes one barrier safe
  }
}

// ---------------- K3: beat segment attention ------------------------------
__global__ __launch_bounds__(256) void k3_battn(
    const float* __restrict__ note_h,
    const float* __restrict__ Wba, const float* __restrict__ bba,
    float* __restrict__ beat_nodes)
{
  const int b = blockIdx.x;
  const int tid = threadIdx.x;
  __shared__ float nh[8][512];
  for (int i = tid; i < 8*512; i += 256)
    nh[i>>9][i&511] = note_h[(size_t)b*8*512 + i];
  __syncthreads();
  for (int dc = 0; dc < 2; ++dc) {
    int d = dc*256 + tid;
    const float* wr = Wba + (size_t)d*512;
    float bb = bba[d];
    float l[8];
#pragma unroll
    for (int n=0;n<8;++n) l[n]=bb;
#pragma unroll 4
    for (int j=0; j<512; ++j) {
      float w = wr[j];
#pragma unroll
      for (int n=0;n<8;++n) l[n] += w*nh[n][j];
    }
    float m = l[0];
#pragma unroll
    for (int n=1;n<8;++n) m = fmaxf(m, l[n]);
    float s = 0.f, o = 0.f;
#pragma unroll
    for (int n=0;n<8;++n) { float e = __expf(l[n]-m); s += e; o += e*nh[n][d]; }
    beat_nodes[(size_t)b*512 + d] = o / s;
  }
}

// ---------------- K4: beat input gates ------------------------------------
__global__ __launch_bounds__(256) void k4_bgates(
    const float* __restrict__ beat_nodes,
    const float* __restrict__ beatWi, const float* __restrict__ beatB,
    float* __restrict__ preB)
{
  const int dir = blockIdx.y, b0 = blockIdx.x*8, tid = threadIdx.x;
  __shared__ float nd[8][512];
  for (int i = tid; i < 8*512; i += 256)
    nd[i>>9][i&511] = beat_nodes[(size_t)b0*512 + i];
  __syncthreads();
  for (int gc = 0; gc < 2; ++gc) {
    int g = gc*256 + tid;
    const float* wr = beatWi + ((size_t)dir*512 + g)*512;
    float bias = beatB[dir*512 + g];
    float acc[8];
#pragma unroll
    for (int n=0;n<8;++n) acc[n]=bias;
#pragma unroll 4
    for (int j=0; j<512; ++j) {
      float w = wr[j];
#pragma unroll
      for (int n=0;n<8;++n) acc[n] += w*nd[n][j];
    }
#pragma unroll
    for (int n=0;n<8;++n)
      preB[((size_t)dir*512 + (b0+n))*512 + g] = acc[n];
  }
}

// ---------------- K5: beat recurrence (H=128, weights in regs) ------------
__global__ __launch_bounds__(512) void k5_brec(
    const float* __restrict__ beatWh,
    const float* __restrict__ preB,
    float* __restrict__ beat_h)
{
  const int dir = blockIdx.x, L = threadIdx.x;
  h16x2 w[64];
  {
    const float2* p = (const float2*)(beatWh + ((size_t)dir*512 + L)*128);
#pragma unroll
    for (int c=0;c<64;++c){
      float2 v = p[c];
      w[c] = f2h2(v.x, v.y);
    }
  }
#pragma unroll
  for (int c=0;c<64;++c) pinv(w[c]);
  __shared__ __align__(16) h16 hb[128];
  __shared__ float gl[512];
  if (L < 128) hb[L] = (h16)0.f;
  float cc = 0.f;
  __syncthreads();
  const bool fwd = (dir == 0);
  for (int it = 0; it < 512; ++it) {
    const int t = fwd ? it : 511 - it;
    float pr = preB[((size_t)dir*512 + t)*512 + L];
    float ac[4] = {0.f,0.f,0.f,0.f};
#pragma unroll
    for (int c=0;c<16;++c){
      U4 hh; hh.u = *(const uint4*)&hb[c*8];
#pragma unroll
      for (int i=0;i<4;++i) ac[i] = fdot2(w[c*4+i], hh.p[i], ac[i]);
    }
    gl[L] = pr + ((ac[0]+ac[1]) + (ac[2]+ac[3]));
    __syncthreads();
    if (L < 128) {
      float gi = gl[L], gf = gl[L+128], gg = gl[L+256], go = gl[L+384];
      cc = sigm(gf)*cc + sigm(gi)*ftanh(gg);
      float h = sigm(go)*ftanh(cc);
      hb[L] = (h16)h;
      beat_h[(size_t)t*256 + dir*128 + L] = h;
    }
    __syncthreads();
  }
}

// ---------------- K6: measure segment attention ---------------------------
__global__ __launch_bounds__(256) void k6_mattn(
    const float* __restrict__ beat_h,
    const float* __restrict__ Wma, const float* __restrict__ bma,
    float* __restrict__ meas_nodes)
{
  const int m = blockIdx.x, tid = threadIdx.x;
  __shared__ float bh[4][256];
  for (int i = tid; i < 4*256; i += 256)
    bh[i>>8][i&255] = beat_h[(size_t)m*4*256 + i];
  __syncthreads();
  int d = tid;
  const float* wr = Wma + (size_t)d*256;
  float bb = bma[d];
  float l[4];
#pragma unroll
  for (int n=0;n<4;++n) l[n]=bb;
#pragma unroll 4
  for (int j=0; j<256; ++j) {
    float w = wr[j];
#pragma unroll
    for (int n=0;n<4;++n) l[n] += w*bh[n][j];
  }
  float mm = fmaxf(fmaxf(l[0],l[1]), fmaxf(l[2],l[3]));
  float s = 0.f, o = 0.f;
#pragma unroll
  for (int n=0;n<4;++n) { float e = __expf(l[n]-mm); s += e; o += e*bh[n][d]; }
  meas_nodes[(size_t)m*256 + d] = o / s;
}

// ---------------- K7: measure input gates ---------------------------------
__global__ __launch_bounds__(256) void k7_mgates(
    const float* __restrict__ meas_nodes,
    const float* __restrict__ measWi, const float* __restrict__ measB,
    float* __restrict__ preM)
{
  const int dir = blockIdx.y, m0 = blockIdx.x*8, tid = threadIdx.x;
  __shared__ float nd[8][256];
  for (int i = tid; i < 8*256; i += 256)
    nd[i>>8][i&255] = meas_nodes[(size_t)m0*256 + i];
  __syncthreads();
  int g = tid;
  const float* wr = measWi + ((size_t)dir*256 + g)*256;
  float bias = measB[dir*256 + g];
  float acc[8];
#pragma unroll
  for (int n=0;n<8;++n) acc[n]=bias;
#pragma unroll 4
  for (int j=0; j<256; ++j) {
    float w = wr[j];
#pragma unroll
    for (int n=0;n<8;++n) acc[n] += w*nd[n][j];
  }
#pragma unroll
  for (int n=0;n<8;++n)
    preM[((size_t)dir*128 + (m0+n))*256 + g] = acc[n];
}

// ---------------- K8: measure recurrence (H=64) ---------------------------
__global__ __launch_bounds__(256, 2) void k8_mrec(
    const float* __restrict__ measWh,
    const float* __restrict__ preM,
    float* __restrict__ meas_h)
{
  const int dir = blockIdx.x, L = threadIdx.x;
  h16x2 w[32];
  {
    const float2* p = (const float2*)(measWh + ((size_t)dir*256 + L)*64);
#pragma unroll
    for (int c=0;c<32;++c){
      float2 v = p[c];
      w[c] = f2h2(v.x, v.y);
    }
  }
#pragma unroll
  for (int c=0;c<32;++c) pinv(w[c]);
  __shared__ __align__(16) h16 hb[64];
  __shared__ float gl[256];
  if (L < 64) hb[L] = (h16)0.f;
  float cc = 0.f;
  __syncthreads();
  const bool fwd = (dir == 0);
  for (int it = 0; it < 128; ++it) {
    const int t = fwd ? it : 127 - it;
    float pr = preM[((size_t)dir*128 + t)*256 + L];
    float ac[4] = {0.f,0.f,0.f,0.f};
#pragma unroll
    for (int c=0;c<8;++c){
      U4 hh; hh.u = *(const uint4*)&hb[c*8];
#pragma unroll
      for (int i=0;i<4;++i) ac[i] = fdot2(w[c*4+i], hh.p[i], ac[i]);
    }
    gl[L] = pr + ((ac[0]+ac[1]) + (ac[2]+ac[3]));
    __syncthreads();
    if (L < 64) {
      float gi = gl[L], gf = gl[L+64], gg = gl[L+128], go = gl[L+192];
      cc = sigm(gf)*cc + sigm(gi)*ftanh(gg);
      float h = sigm(go)*ftanh(cc);
      hb[L] = (h16)h;
      meas_h[(size_t)t*128 + dir*64 + L] = h;
    }
    __syncthreads();
  }
}

// ---------------- K9: scan known-part GEMM (pre_out + pre_fc) -------------
// pre_out now written GATE-INTERLEAVED: [t][elem j][gate] (float4 per elem)
__global__ __launch_bounds__(256) void k9_scanpre(
    const float* __restrict__ note_h, const float* __restrict__ voice_h,
    const float* __restrict__ beat_h, const float* __restrict__ meas_h,
    const float* __restrict__ xf,
    const h16* __restrict__ outWiF, const h16* __restrict__ WfcKF,
    const float* __restrict__ outB, const float* __restrict__ bfc,
    float* __restrict__ pre_out, float* __restrict__ pre_fc)
{
  const int t0 = blockIdx.x*8, tid = threadIdx.x;
  __shared__ __align__(16) h16 kn[8][1416];
  const float qpm = xf[5], tp0 = xf[76], tp1 = xf[77];
  for (int i = tid; i < 8*1416; i += 256) {
    int tt = i/1416, c = i - tt*1416;
    int t = t0 + tt;
    float v;
    if (c < 512) v = note_h[(size_t)t*512 + c];
    else if (c < 768) v = beat_h[(size_t)(t>>3)*256 + (c-512)];
    else if (c < 896) v = meas_h[(size_t)(t>>5)*128 + (c-768)];
    else if (c < 1408) v = voice_h[(size_t)t*512 + (c-896)];
    else if (c == 1408) v = qpm;
    else if (c == 1409) v = tp0;
    else if (c == 1410) v = tp1;
    else v = 0.f;
    kn[tt][c] = (h16)v;
  }
  __syncthreads();
  for (int rr = 0; rr < 3; ++rr) {
    int r = (rr < 2) ? (tid + rr*256) : (512 + tid);
    if (rr == 2 && tid >= 10) break;
    const h16* wrow = (r < 512) ? (outWiF + (size_t)r*1416) : (WfcKF + (size_t)(r-512)*1416);
    float bias = (r < 512) ? outB[r] : bfc[r-512];
    float acc[8];
#pragma unroll
    for (int tt=0;tt<8;++tt) acc[tt] = bias;
    for (int cu = 0; cu < 177; ++cu) {
      U4 wv; wv.u = *(const uint4*)(wrow + cu*8);
#pragma unroll
      for (int tt=0; tt<8; ++tt) {
        U4 kv; kv.u = *(const uint4*)&kn[tt][cu*8];
#pragma unroll
        for (int i=0;i<4;++i) acc[tt] = fdot2(wv.p[i], kv.p[i], acc[tt]);
      }
    }
#pragma unroll
    for (int tt=0; tt<8; ++tt) {
      if (r < 512) pre_out[((size_t)(t0+tt)*128 + (r & 127))*4 + (r >> 7)] = acc[tt];
      else pre_fc[(size_t)(t0+tt)*16 + (r-512)] = acc[tt];
    }
  }
}

// ---------------- K9b: bt-LSTM known-part gates ---------------------------
// pre_bt now written GATE-INTERLEAVED: [b][elem j][gate]
__global__ __launch_bounds__(256) void k9b_btpre(
    const float* __restrict__ beat_h, const float* __restrict__ xf,
    const float* __restrict__ btWi, const float* __restrict__ btB,
    float* __restrict__ pre_bt)
{
  const int b0 = blockIdx.x*8, tid = threadIdx.x;
  __shared__ float bh[8][256];
  __shared__ float btv[8][3];
  for (int i = tid; i < 8*256; i += 256)
    bh[i>>8][i&255] = beat_h[(size_t)b0*256 + i];
  if (tid < 24) {
    int n = tid/3, j = tid - n*3;
    btv[n][j] = xf[(size_t)(b0+n)*8*78 + 28 + j];
  }
  __syncthreads();
  const float qpm = xf[5], tp0 = xf[76], tp1 = xf[77];
  for (int gc = 0; gc < 2; ++gc) {
    int g = gc*256 + tid;
    const float* row = btWi + (size_t)g*273;
    float bias = btB[g];
    float acc[8];
#pragma unroll
    for (int n=0;n<8;++n) acc[n]=bias;
#pragma unroll 4
    for (int j = 0; j < 256; ++j) {
      float w = row[j];
#pragma unroll
      for (int n=0;n<8;++n) acc[n] += w*bh[n][j];
    }
    float w257 = row[257], w258 = row[258], w259 = row[259];
    float w260 = row[260], w261 = row[261], w262 = row[262];
#pragma unroll
    for (int n=0;n<8;++n) {
      acc[n] += w257*qpm + w258*tp0 + w259*tp1
              + w260*btv[n][0] + w261*btv[n][1] + w262*btv[n][2];
      pre_bt[((size_t)(b0+n)*128 + (g & 127))*4 + (g >> 7)] = acc[n];
    }
  }
}

// ---------------- K10: the grand sequential scan --------------------------
// v3: gate-owner + in-wave column-split (the k2 round-2 trick applied here).
// Thread (j,q): j = wid*16 + (lane&15) = element 0..127; q = lane>>4 =
// column quarter. Each thread holds ALL FOUR gate rows of element j over
// 32 cols (4x16 h16x2). Partials reduce via __shfl_xor(16/32); cell runs
// redundantly in all 4 copies -> gl/gb LDS exchange deleted; 2 barriers per
// non-beat step:
//   phase1: finish gates (+seq/pre on the q==g copy), cell, q==0 writes oh16
//   B1
//   phase2: recurrent dot for t+1 (all) || wave0: C2/D/E epilogue
//   B2 (pofc/buf/ptvS visible for next phase1)
// pre_out/pre_bt are gate-interleaved (k9/k9b) -> one coalesced scalar each.
__global__ __launch_bounds__(512) __attribute__((amdgpu_waves_per_eu(2, 2)))
void k10_scan(
    const float* __restrict__ pre_out, const float* __restrict__ pre_fc,
    const float* __restrict__ pre_bt,
    const float* __restrict__ outWh, const float* __restrict__ btWh,
    const float* __restrict__ outWi, const float* __restrict__ btWi,
    const float* __restrict__ Wfc,
    const float* __restrict__ Wta, const float* __restrict__ bta,
    const float* __restrict__ Wt1, const float* __restrict__ bt1,
    const float* __restrict__ Wt2, const float* __restrict__ bt2,
    const float* __restrict__ yf,
    float* __restrict__ out)
{
  const int L = threadIdx.x;
  const int lane = L & 63;
  const int wid  = L >> 6;          // 0..7
  const int jl   = lane & 15;
  const int q    = lane >> 4;       // column quarter 0..3
  const int j    = wid*16 + jl;     // element 0..127
  const int row  = q*128 + j;       // gate row this copy adds seq/pre for

  // weights: 4 gates x cols [q*32, q*32+32)
  h16x2 owh[4][16], btw[4][16];
#pragma unroll
  for (int g=0; g<4; ++g) {
    const float2* p  = (const float2*)(outWh + (size_t)(g*128 + j)*128 + q*32);
    const float2* pb = (const float2*)(btWh  + (size_t)(g*128 + j)*128 + q*32);
#pragma unroll
    for (int c=0;c<16;++c){
      float2 a = p[c];  owh[g][c] = f2h2(a.x, a.y);
      float2 b = pb[c]; btw[g][c] = f2h2(b.x, b.y);
    }
  }
#pragma unroll
  for (int g=0; g<4; ++g)
#pragma unroll
    for (int c=0;c<16;++c) pinv(owh[g][c]);

  float oseq[13];
#pragma unroll
  for (int jj=0;jj<13;++jj) oseq[jj] = outWi[(size_t)row*1424 + 1408 + jj];
  float btpt = btWi[(size_t)row*273 + 256];
  float btrn[10];
#pragma unroll
  for (int d=0;d<10;++d) btrn[d] = btWi[(size_t)row*273 + 263 + d];

  __shared__ __align__(16) h16 oh16[128];
  __shared__ __align__(16) h16 th16[128];
  __shared__ __align__(16) h16 Wt1f[128*136];  // f16, padded row stride 136
  __shared__ __align__(16) h16 WfcD[10*128];
  __shared__ __align__(16) float pofc[16];
  __shared__ float ptvS;
  __shared__ float buf[8][10];
  __shared__ float rn[10], att[8][10], r1v[128], ytail[10];
  __shared__ float WfcSeq[10][13];
  __shared__ float WtaS[100], btaS[10], Wt2S[128], bt1S[128], bt2S;

  for (int i=L; i<128*128; i+=512) Wt1f[(i>>7)*136 + (i&127)] = (h16)Wt1[i];
  for (int i=L; i<10*128; i+=512)  WfcD[i] = (h16)Wfc[(size_t)(i>>7)*1552 + (i&127)];
  if (L < 100) WtaS[L] = Wta[L];
  if (L < 10)  btaS[L] = bta[L];
  if (L < 128) { Wt2S[L] = Wt2[L]; bt1S[L] = bt1[L]; }
  if (L == 0)  bt2S = bt2[0];
  if (L < 128) { oh16[L] = (h16)0.f; th16[L] = (h16)0.f; }
  if (L < 11) pofc[L] = yf[L];
  if (L >= 11 && L < 16) pofc[L] = 0.f;
  if (L == 0) ptvS = yf[0];
  if (L < 10) ytail[L] = yf[1+L];
  if (L < 80) buf[L/10][L%10] = 0.f;
  if (L < 130) WfcSeq[L/13][L%13] = Wfc[(size_t)(L/13)*1552 + 1536 + (L%13)];
  float oc = 0.f, tc = 0.f;
  float ac4[4]  = {0.f,0.f,0.f,0.f};   // Owh·h(t-1) partials (h(-1)=0)
  float acB4[4] = {0.f,0.f,0.f,0.f};   // BtWh·th(prev beat) partials
  const int dD = L >> 2, qD = L & 3;
  const float* ppo = pre_out + (size_t)j*4 + q;   // [t][j][gate] stride 512
  const float* ppb = pre_bt  + (size_t)j*4 + q;   // [b][j][gate] stride 512
  float prv  = *ppo; ppo += 512;
  float prbt = *ppb; ppb += 512;
  float prfc = (L < 40 && qD == 0) ? pre_fc[dD] : 0.f;
  const float* pp_fc = pre_fc + 16 + dD;
  __syncthreads();

  for (int t = 0; t < NT; ++t) {
    const bool isb = (t & 7) == 0;
    if (isb) {
      if (t == 0) {
        if (L < 10) rn[L] = ytail[L];
      } else {
        if (L < 80) {
          int n = L/10, d = L - n*10;
          float s = btaS[d];
#pragma unroll
          for (int jj=0;jj<10;++jj) s += buf[n][jj]*WtaS[d*10 + jj];
          att[n][d] = s;
        }
        __syncthreads();
        if (L < 10) {
          float m = att[0][L];
#pragma unroll
          for (int n=1;n<8;++n) m = fmaxf(m, att[n][L]);
          float s = 0.f, acc = 0.f;
#pragma unroll
          for (int n=0;n<8;++n) { float e = __expf(att[n][L]-m); s += e; acc += e*buf[n][L]; }
          rn[L] = acc/s;
        }
      }
      __syncthreads();
    }
    // ---- phase 1: finish gates + cells ----
    {
      float4 pf0 = *(const float4*)&pofc[0];
      float4 pf1 = *(const float4*)&pofc[4];
      float4 pf2 = *(const float4*)&pofc[8];
      float  pcc = pofc[12];
      float ex = prv;
      ex += oseq[0]*pf0.x + oseq[1]*pf0.y + oseq[2]*pf0.z + oseq[3]*pf0.w;
      ex += oseq[4]*pf1.x + oseq[5]*pf1.y + oseq[6]*pf1.z + oseq[7]*pf1.w;
      ex += oseq[8]*pf2.x + oseq[9]*pf2.y + oseq[10]*pf2.z + oseq[11]*pf2.w;
      ex += oseq[12]*pcc;
      prv = *ppo; ppo += 512;            // safe over-read at t=NT-1
      float p0 = ac4[0] + ((q==0) ? ex : 0.f);
      float p1 = ac4[1] + ((q==1) ? ex : 0.f);
      float p2 = ac4[2] + ((q==2) ? ex : 0.f);
      float p3 = ac4[3] + ((q==3) ? ex : 0.f);
      p0 += __shfl_xor(p0, 16, 64); p0 += __shfl_xor(p0, 32, 64);
      p1 += __shfl_xor(p1, 16, 64); p1 += __shfl_xor(p1, 32, 64);
      p2 += __shfl_xor(p2, 16, 64); p2 += __shfl_xor(p2, 32, 64);
      p3 += __shfl_xor(p3, 16, 64); p3 += __shfl_xor(p3, 32, 64);
      oc = sigm(p1)*oc + sigm(p0)*ftanh(p2);
      float nh = sigm(p3)*ftanh(oc);
      if (q == 0) oh16[j] = (h16)nh;
    }
    if (isb) {
      float ex = prbt + btpt*ptvS;
#pragma unroll
      for (int d=0;d<10;++d) ex += btrn[d]*rn[d];
      prbt = *ppb; ppb += 512;           // safe over-read at last beat
      float p0 = acB4[0] + ((q==0) ? ex : 0.f);
      float p1 = acB4[1] + ((q==1) ? ex : 0.f);
      float p2 = acB4[2] + ((q==2) ? ex : 0.f);
      float p3 = acB4[3] + ((q==3) ? ex : 0.f);
      p0 += __shfl_xor(p0, 16, 64); p0 += __shfl_xor(p0, 32, 64);
      p1 += __shfl_xor(p1, 16, 64); p1 += __shfl_xor(p1, 32, 64);
      p2 += __shfl_xor(p2, 16, 64); p2 += __shfl_xor(p2, 32, 64);
      p3 += __shfl_xor(p3, 16, 64); p3 += __shfl_xor(p3, 32, 64);
      tc = sigm(p1)*tc + sigm(p0)*ftanh(p2);
      float nth = sigm(p3)*ftanh(tc);
      if (q == 0) th16[j] = (h16)nth;
    }
    __syncthreads();                     // B1: oh16 (and th16) visible
    // ---- phase 2: recurrent partials for t+1 + epilogue ----
    {
      float a0=0.f,a1=0.f,a2=0.f,a3=0.f;
#pragma unroll
      for (int cb=0; cb<4; ++cb) {
        U4 hh; hh.u = *(const uint4*)&oh16[q*32 + cb*8];
#pragma unroll
        for (int i=0;i<4;++i) {
          a0 = fdot2(owh[0][cb*4+i], hh.p[i], a0);
          a1 = fdot2(owh[1][cb*4+i], hh.p[i], a1);
          a2 = fdot2(owh[2][cb*4+i], hh.p[i], a2);
          a3 = fdot2(owh[3][cb*4+i], hh.p[i], a3);
        }
      }
      ac4[0]=a0; ac4[1]=a1; ac4[2]=a2; ac4[3]=a3;
    }
    if (((t+1) & 7) == 0) {              // th16 stable until next beat's phase1
      float b0=0.f,b1=0.f,b2=0.f,b3=0.f;
#pragma unroll
      for (int cb=0; cb<4; ++cb) {
        U4 hh; hh.u = *(const uint4*)&th16[q*32 + cb*8];
#pragma unroll
        for (int i=0;i<4;++i) {
          b0 = fdot2(btw[0][cb*4+i], hh.p[i], b0);
          b1 = fdot2(btw[1][cb*4+i], hh.p[i], b1);
          b2 = fdot2(btw[2][cb*4+i], hh.p[i], b2);
          b3 = fdot2(btw[3][cb*4+i], hh.p[i], b3);
        }
      }
      acB4[0]=b0; acB4[1]=b1; acB4[2]=b2; acB4[3]=b3;
    }
    // C1: tempo hidden layer (beat steps; Wt1 f16 in LDS, th16 = new nth)
    if (isb) {
      if (L < 128) {
        float ac[4] = {0.f,0.f,0.f,0.f};
        const h16* wrow = &Wt1f[L*136];
#pragma unroll
        for (int k=0;k<16;++k){
          U4 wv; wv.u = *(const uint4*)(wrow + k*8);
          U4 hh; hh.u = *(const uint4*)&th16[k*8];
#pragma unroll
          for (int i=0;i<4;++i) ac[i] = fdot2(wv.p[i], hh.p[i], ac[i]);
        }
        float s = bt1S[L] + ((ac[0]+ac[1]) + (ac[2]+ac[3]));
        r1v[L] = fmaxf(s, 0.f);
      }
      __syncthreads();
    }
    // wave 0: C2 (ptv) + D (out_fc) + E (epilogue)
    if (L < 64) {
      float ptv_l;
      if (isb) {
        float p = Wt2S[L]*r1v[L] + Wt2S[L+64]*r1v[L+64];
#pragma unroll
        for (int sft=32; sft>0; sft>>=1) p += __shfl_xor(p, sft, 64);
        ptv_l = p + bt2S;
        if (L == 0) ptvS = ptv_l;
      } else {
        ptv_l = ptvS;
      }
      // D
      float s = 0.f;
      if (L < 40) {
        const h16* wr = &WfcD[dD*128 + qD*32];
#pragma unroll
        for (int jj=0;jj<32;++jj) s += (float)wr[jj] * (float)oh16[qD*32 + jj];
      }
      s += __shfl_xor(s, 1, 64);
      s += __shfl_xor(s, 2, 64);
      float e = 0.f;
      if (L < 40 && qD == 0) {
        e = prfc;
#pragma unroll
        for (int jj=0;jj<13;++jj) e += WfcSeq[dD][jj]*pofc[jj];
        prfc = *pp_fc; pp_fc += 16;      // safe over-read at t=NT-1
      }
      float ofc = s + e;                 // final at lanes 4d, d<10
      // E
      int srcE = (L >= 1 && L < 11) ? 4*(L-1) : ((L >= 11 && L < 13) ? 4*(L-11) : 0);
      float valE = __shfl(ofc, srcE, 64);
      float bval = __shfl(ofc, 4*(L & 15), 64);
      if (L == 0)      { out[(size_t)t*11] = ptv_l; pofc[0] = ptv_l; }
      else if (L < 11) { out[(size_t)t*11 + L] = valE; pofc[L] = valE; }
      else if (L < 13) { pofc[L] = valE; }
      if (L < 10) buf[t & 7][L] = bval;
    }
    __syncthreads();                     // B2: pofc/buf/ptvS for next step
  }
}

// ---------------- launcher ------------------------------------------------
extern "C" void kernel_launch(void* const* d_in, const int* in_sizes, int n_in,
                              void* d_out, int out_size, void* d_ws, size_t ws_size,
                              hipStream_t stream)
{
  const float* x      = (const float*)d_in[0];
  const float* y      = (const float*)d_in[1];
  const float* noteWi = (const float*)d_in[4];
  const float* noteWh = (const float*)d_in[5];
  const float* noteB  = (const float*)d_in[6];
  const float* voiceWi= (const float*)d_in[7];
  const float* voiceWh= (const float*)d_in[8];
  const float* voiceB = (const float*)d_in[9];
  const float* beatWi = (const float*)d_in[10];
  const float* beatWh = (const float*)d_in[11];
  const float* beatB  = (const float*)d_in[12];
  const float* measWi = (const float*)d_in[13];
  const float* measWh = (const float*)d_in[14];
  const float* measB  = (const float*)d_in[15];
  const float* Wba    = (const float*)d_in[16];
  const float* bba    = (const float*)d_in[17];
  const float* Wma    = (const float*)d_in[18];
  const float* bma    = (const float*)d_in[19];
  const float* Wta    = (const float*)d_in[20];
  const float* bta    = (const float*)d_in[21];
  const float* outWi  = (const float*)d_in[22];
  const float* outWh  = (const float*)d_in[23];
  const float* outB   = (const float*)d_in[24];
  const float* Wfc    = (const float*)d_in[25];
  const float* bfc    = (const float*)d_in[26];
  const float* btWi   = (const float*)d_in[27];
  const float* btWh   = (const float*)d_in[28];
  const float* btB    = (const float*)d_in[29];
  const float* Wt1    = (const float*)d_in[30];
  const float* bt1    = (const float*)d_in[31];
  const float* Wt2    = (const float*)d_in[32];
  const float* bt2    = (const float*)d_in[33];

  float* fws = (float*)d_ws;
  float* note_h     = fws + 0;
  float* voice_h    = fws + 2097152;
  float* beat_nodes = fws + 4194304;
  float* preB       = fws + 4456448;
  float* beat_h     = fws + 4980736;
  float* meas_nodes = fws + 5111808;
  float* preM       = fws + 5144576;
  float* meas_h     = fws + 5210112;
  float* pre_out    = fws + 5226496;
  float* pre_fc     = fws + 7323648;
  float* pre_bt     = fws + 7389184;
  h16* hws   = (h16*)(fws + 7651328);
  h16* preNV  = hws;
  h16* WhF    = hws + 16777216;
  h16* outWiF = hws + 17825792;
  h16* WfcKF  = hws + 18550784;

  float* out_outs  = (float*)d_out;
  float* out_noteh = out_outs + OUTS_OFF;

  hipLaunchKernelGGL(k0_prep, dim3(1024), dim3(256), 0, stream,
                     noteWh, voiceWh, outWi, Wfc, WhF, outWiF, WfcKF);
  hipLaunchKernelGGL(k1_xgates, dim3(256,4), dim3(256), 0, stream,
                     x, noteWi, noteB, voiceWi, voiceB, preNV);
  hipLaunchKernelGGL(k2_nvrec, dim3(4), dim3(512), 0, stream,
                     WhF, preNV, note_h, voice_h, out_noteh);
  hipLaunchKernelGGL(k3_battn, dim3(512), dim3(256), 0, stream,
                     note_h, Wba, bba, beat_nodes);
  hipLaunchKernelGGL(k4_bgates, dim3(64,2), dim3(256), 0, stream,
                     beat_nodes, beatWi, beatB, preB);
  hipLaunchKernelGGL(k5_brec, dim3(2), dim3(512), 0, stream,
                     beatWh, preB, beat_h);
  hipLaunchKernelGGL(k6_mattn, dim3(128), dim3(256), 0, stream,
                     beat_h, Wma, bma, meas_nodes);
  hipLaunchKernelGGL(k7_mgates, dim3(16,2), dim3(256), 0, stream,
                     meas_nodes, measWi, measB, preM);
  hipLaunchKernelGGL(k8_mrec, dim3(2), dim3(256), 0, stream,
                     measWh, preM, meas_h);
  hipLaunchKernelGGL(k9b_btpre, dim3(64), dim3(256), 0, stream,
                     beat_h, x, btWi, btB, pre_bt);
  hipLaunchKernelGGL(k9_scanpre, dim3(512), dim3(256), 0, stream,
                     note_h, voice_h, beat_h, meas_h, x, outWiF, WfcKF, outB, bfc, pre_out, pre_fc);
  hipLaunchKernelGGL(k10_scan, dim3(1), dim3(512), 0, stream,
                     pre_out, pre_fc, pre_bt, outWh, btWh, outWi, btWi, Wfc,
                     Wta, bta, Wt1, bt1, Wt2, bt2, y, out_outs);
}

// Round 7
// 13993.964 us; speedup vs baseline: 1.4164x; 1.0023x over previous
//
#include <hip/hip_runtime.h>
#include <hip/hip_bf16.h>

typedef unsigned int u32;
typedef _Float16 h16;
typedef __attribute__((ext_vector_type(2))) _Float16 h16x2;

union U4 { uint4 u; h16x2 p[4]; };
union U4H { uint4 u; h16 h[8]; };

static __device__ __forceinline__ float sigm(float x){ return 1.0f / (1.0f + __expf(-x)); }
static __device__ __forceinline__ float ftanh(float x){ return 1.0f - 2.0f/(1.0f + __expf(2.0f*x)); }
static __device__ __forceinline__ h16x2 f2h2(float a, float b){
  h16x2 r; r[0] = (h16)a; r[1] = (h16)b; return r;
}
// Pin a packed-f16 pair into an arch-VGPR (defeats AGPR-parking / remat).
static __device__ __forceinline__ void pinv(h16x2 &x){
  u32 t = __builtin_bit_cast(u32, x);
  asm volatile("" : "+v"(t));
  x = __builtin_bit_cast(h16x2, t);
}

// NOTE (round-6 post-mortem): forcing single-inst v_dot2_f32_f16 via inline
// asm changes rounding vs this builtin path and breaks the 4096-step LSTM
// trajectory past the absmax threshold (1.39e-2 > 8.7e-3). Keep the builtin.
#if defined(__has_builtin)
#if __has_builtin(__builtin_amdgcn_fdot2)
#define FDOT2_NATIVE 1
#endif
#endif
static __device__ __forceinline__ float fdot2(h16x2 a, h16x2 b, float c){
#ifdef FDOT2_NATIVE
  return __builtin_amdgcn_fdot2(a, b, c, false);
#else
  return c + (float)a[0]*(float)b[0] + (float)a[1]*(float)b[1];
#endif
}

#define NT 4096
#define OUTS_OFF 45056

// ---------------- K0: weight conversions (f32 -> f16, packed layouts) ----
__global__ __launch_bounds__(256) void k0_prep(
    const float* __restrict__ noteWh, const float* __restrict__ voiceWh,
    const float* __restrict__ outWi,  const float* __restrict__ Wfc,
    h16* __restrict__ WhF, h16* __restrict__ outWiF, h16* __restrict__ WfcKF)
{
  const int NWH = 4*1024*256;     // 1048576
  const int NOW = 512*1416;       // 724992
  const int NFC = 10*1416;        // 14160
  for (int i = blockIdx.x*256 + threadIdx.x; i < NWH + NOW + NFC; i += gridDim.x*256) {
    if (i < NWH) {
      int dir = i >> 18;
      int rem = i & 262143;
      const float* src = (dir < 2) ? noteWh : voiceWh;
      WhF[i] = (h16)src[((dir & 1) << 18) + rem];
    } else if (i < NWH + NOW) {
      int j = i - NWH;
      int r = j / 1416, c = j - r*1416;
      float v = 0.f;
      if (c < 1408) v = outWi[(size_t)r*1424 + c];
      else if (c < 1411) v = outWi[(size_t)r*1424 + 1421 + (c-1408)];
      outWiF[j] = (h16)v;
    } else {
      int j = i - NWH - NOW;
      int r = j / 1416, c = j - r*1416;
      float v = 0.f;
      if (c < 1408) v = Wfc[(size_t)r*1552 + 128 + c];
      else if (c < 1411) v = Wfc[(size_t)r*1552 + 1549 + (c-1408)];
      WfcKF[j] = (h16)v;
    }
  }
}

// ---------------- K1: note/voice input gates: pre = b + Wi @ x ------------
// preNV layout: [dir][t][e*4 + gate]  (gate-interleaved so K2 loads one u2)
__global__ __launch_bounds__(256) void k1_xgates(
    const float* __restrict__ x,
    const float* __restrict__ noteWi, const float* __restrict__ noteB,
    const float* __restrict__ voiceWi, const float* __restrict__ voiceB,
    h16* __restrict__ preNV)
{
  const int dir = blockIdx.y;
  const int t0  = blockIdx.x * 16;
  const int tid = threadIdx.x;
  __shared__ float xs[16][80];
  for (int i = tid; i < 16*78; i += 256) {
    int tt = i / 78, j = i - tt*78;
    xs[tt][j] = x[(size_t)(t0+tt)*78 + j];
  }
  __syncthreads();
  const float* Wi = (dir < 2) ? noteWi : voiceWi;
  const float* B  = (dir < 2) ? noteB  : voiceB;
  const int dw = dir & 1;
  for (int gc = 0; gc < 4; ++gc) {
    int g = gc*256 + tid;
    const float* row = Wi + ((size_t)dw*1024 + g)*78;
    float bias = B[dw*1024 + g];
    float acc[16];
#pragma unroll
    for (int tt=0; tt<16; ++tt) acc[tt] = bias;
#pragma unroll 6
    for (int j=0; j<78; ++j) {
      float w = row[j];
#pragma unroll
      for (int tt=0; tt<16; ++tt)
        acc[tt] += w*xs[tt][j];
    }
#pragma unroll
    for (int tt=0; tt<16; ++tt)
      preNV[((size_t)dir*NT + (t0+tt))*1024 + (tid*4 + gc)] = (h16)acc[tt];
  }
}

// ---------------- K2: note/voice recurrences (4 dirs, 1 block each) -------
// EXACT round-2 form (measured 6.50 ms): launch_bounds(512,2), no
// waves_per_eu attr (adding it cost +0.37 ms in r4/r5), builtin fdot2.
__global__ __launch_bounds__(512, 2)
void k2_nvrec(
    const h16* __restrict__ WhF,
    const h16* __restrict__ preNV,
    float* __restrict__ note_h,
    float* __restrict__ voice_h,
    float* __restrict__ out_noteh)
{
  const int dir = blockIdx.x;
  const int L = threadIdx.x;
  const int lane = L & 63;
  const int wid  = L >> 6;           // 0..7
  const int hi   = lane >> 5;        // column half
  const int e    = wid*32 + (lane & 31);   // element 0..255
  const int c0   = hi*128;
  const h16* Wb = WhF + (size_t)dir*1024*256;

  // Register weights: cols c0..c0+95, gates 0..3 (i,f,g,o)
  h16x2 w[4][48];
#pragma unroll
  for (int g=0; g<4; ++g) {
    const h16* row = Wb + (size_t)(g*256 + e)*256 + c0;
#pragma unroll
    for (int cb=0; cb<12; ++cb) {
      U4 a; a.u = *(const uint4*)(row + cb*8);
#pragma unroll
      for (int i=0;i<4;++i) w[g][cb*4+i] = a.p[i];
    }
  }
#pragma unroll
  for (int g=0; g<4; ++g)
#pragma unroll
    for (int c=0;c<48;++c) pinv(w[g][c]);

  // LDS weights: cols c0+96..c0+127, lane-dense: [(cb*4+g)*2+hi][e][8]
  __shared__ __align__(16) h16 Wl[4*4*2*256*8];   // 128 KiB
  __shared__ __align__(16) h16 hb[2][256];
#pragma unroll
  for (int cb=0; cb<4; ++cb)
#pragma unroll
    for (int g=0; g<4; ++g) {
      const h16* src = Wb + (size_t)(g*256 + e)*256 + c0 + 96 + cb*8;
      *(uint4*)&Wl[(size_t)((((cb*4+g)*2 + hi)*256 + e))*8] = *(const uint4*)src;
    }
  if (hi == 0) hb[0][e] = (h16)0.f;
  float cc = 0.f;
  __syncthreads();

  const bool fwd = ((dir & 1) == 0);
  const bool isNote = (dir < 2);
  float* hout = isNote ? note_h : voice_h;
  const int half = (dir & 1) * 256;
  const h16* pre = preNV + (size_t)dir*NT*1024;
  int cur = 0;
  const int step = fwd ? 1 : -1;
  int t = fwd ? 0 : NT-1;

  union PU { uint2 u; h16 h[4]; };
  PU pv_n; pv_n.u = *(const uint2*)(pre + (size_t)t*1024 + e*4);

  for (int it = 0; it < NT; ++it, t += step) {
    PU pv = pv_n;
    if (it+1 < NT) pv_n.u = *(const uint2*)(pre + (size_t)(t+step)*1024 + e*4);

    float ac[4][2] = {{0.f,0.f},{0.f,0.f},{0.f,0.f},{0.f,0.f}};
    // register-resident columns
#pragma unroll
    for (int cb=0; cb<12; ++cb) {
      U4 hh; hh.u = *(const uint4*)&hb[cur][c0 + cb*8];
#pragma unroll
      for (int i=0;i<4;++i) {
        ac[0][i&1] = fdot2(w[0][cb*4+i], hh.p[i], ac[0][i&1]);
        ac[1][i&1] = fdot2(w[1][cb*4+i], hh.p[i], ac[1][i&1]);
        ac[2][i&1] = fdot2(w[2][cb*4+i], hh.p[i], ac[2][i&1]);
        ac[3][i&1] = fdot2(w[3][cb*4+i], hh.p[i], ac[3][i&1]);
      }
    }
    // LDS-resident columns
#pragma unroll
    for (int cb=0; cb<4; ++cb) {
      U4 hh; hh.u = *(const uint4*)&hb[cur][c0 + 96 + cb*8];
#pragma unroll
      for (int g=0; g<4; ++g) {
        U4 wv; wv.u = *(const uint4*)&Wl[(size_t)((((cb*4+g)*2 + hi)*256 + e))*8];
#pragma unroll
        for (int i=0;i<4;++i) ac[g][i&1] = fdot2(wv.p[i], hh.p[i], ac[g][i&1]);
      }
    }
    // combine halves within the wave (lane ^ 32)
    float g4[4];
#pragma unroll
    for (int g=0; g<4; ++g) {
      float s = ac[g][0] + ac[g][1];
      s += __shfl_xor(s, 32, 64);
      g4[g] = s;
    }
    // cell (both halves compute identically; hi==0 writes)
    float gi = (float)pv.h[0] + g4[0];
    float gf = (float)pv.h[1] + g4[1];
    float gg = (float)pv.h[2] + g4[2];
    float go = (float)pv.h[3] + g4[3];
    cc = sigm(gf)*cc + sigm(gi)*ftanh(gg);
    float h = sigm(go)*ftanh(cc);
    if (hi == 0) {
      hb[cur^1][e] = (h16)h;
      hout[(size_t)t*512 + half + e] = h;
      if (isNote) out_noteh[(size_t)t*512 + half + e] = h;
    }
    cur ^= 1;
    __syncthreads();   // new h visible; ping-pong makes one barrier safe
  }
}

// ---------------- K3: beat segment attention ------------------------------
__global__ __launch_bounds__(256) void k3_battn(
    const float* __restrict__ note_h,
    const float* __restrict__ Wba, const float* __restrict__ bba,
    float* __restrict__ beat_nodes)
{
  const int b = blockIdx.x;
  const int tid = threadIdx.x;
  __shared__ float nh[8][512];
  for (int i = tid; i < 8*512; i += 256)
    nh[i>>9][i&511] = note_h[(size_t)b*8*512 + i];
  __syncthreads();
  for (int dc = 0; dc < 2; ++dc) {
    int d = dc*256 + tid;
    const float* wr = Wba + (size_t)d*512;
    float bb = bba[d];
    float l[8];
#pragma unroll
    for (int n=0;n<8;++n) l[n]=bb;
#pragma unroll 4
    for (int j=0; j<512; ++j) {
      float w = wr[j];
#pragma unroll
      for (int n=0;n<8;++n) l[n] += w*nh[n][j];
    }
    float m = l[0];
#pragma unroll
    for (int n=1;n<8;++n) m = fmaxf(m, l[n]);
    float s = 0.f, o = 0.f;
#pragma unroll
    for (int n=0;n<8;++n) { float e = __expf(l[n]-m); s += e; o += e*nh[n][d]; }
    beat_nodes[(size_t)b*512 + d] = o / s;
  }
}

// ---------------- K4: beat input gates ------------------------------------
__global__ __launch_bounds__(256) void k4_bgates(
    const float* __restrict__ beat_nodes,
    const float* __restrict__ beatWi, const float* __restrict__ beatB,
    float* __restrict__ preB)
{
  const int dir = blockIdx.y, b0 = blockIdx.x*8, tid = threadIdx.x;
  __shared__ float nd[8][512];
  for (int i = tid; i < 8*512; i += 256)
    nd[i>>9][i&511] = beat_nodes[(size_t)b0*512 + i];
  __syncthreads();
  for (int gc = 0; gc < 2; ++gc) {
    int g = gc*256 + tid;
    const float* wr = beatWi + ((size_t)dir*512 + g)*512;
    float bias = beatB[dir*512 + g];
    float acc[8];
#pragma unroll
    for (int n=0;n<8;++n) acc[n]=bias;
#pragma unroll 4
    for (int j=0; j<512; ++j) {
      float w = wr[j];
#pragma unroll
      for (int n=0;n<8;++n) acc[n] += w*nd[n][j];
    }
#pragma unroll
    for (int n=0;n<8;++n)
      preB[((size_t)dir*512 + (b0+n))*512 + g] = acc[n];
  }
}

// ---------------- K5: beat recurrence (H=128, weights in regs) ------------
__global__ __launch_bounds__(512) void k5_brec(
    const float* __restrict__ beatWh,
    const float* __restrict__ preB,
    float* __restrict__ beat_h)
{
  const int dir = blockIdx.x, L = threadIdx.x;
  h16x2 w[64];
  {
    const float2* p = (const float2*)(beatWh + ((size_t)dir*512 + L)*128);
#pragma unroll
    for (int c=0;c<64;++c){
      float2 v = p[c];
      w[c] = f2h2(v.x, v.y);
    }
  }
#pragma unroll
  for (int c=0;c<64;++c) pinv(w[c]);
  __shared__ __align__(16) h16 hb[128];
  __shared__ float gl[512];
  if (L < 128) hb[L] = (h16)0.f;
  float cc = 0.f;
  __syncthreads();
  const bool fwd = (dir == 0);
  for (int it = 0; it < 512; ++it) {
    const int t = fwd ? it : 511 - it;
    float pr = preB[((size_t)dir*512 + t)*512 + L];
    float ac[4] = {0.f,0.f,0.f,0.f};
#pragma unroll
    for (int c=0;c<16;++c){
      U4 hh; hh.u = *(const uint4*)&hb[c*8];
#pragma unroll
      for (int i=0;i<4;++i) ac[i] = fdot2(w[c*4+i], hh.p[i], ac[i]);
    }
    gl[L] = pr + ((ac[0]+ac[1]) + (ac[2]+ac[3]));
    __syncthreads();
    if (L < 128) {
      float gi = gl[L], gf = gl[L+128], gg = gl[L+256], go = gl[L+384];
      cc = sigm(gf)*cc + sigm(gi)*ftanh(gg);
      float h = sigm(go)*ftanh(cc);
      hb[L] = (h16)h;
      beat_h[(size_t)t*256 + dir*128 + L] = h;
    }
    __syncthreads();
  }
}

// ---------------- K6: measure segment attention ---------------------------
__global__ __launch_bounds__(256) void k6_mattn(
    const float* __restrict__ beat_h,
    const float* __restrict__ Wma, const float* __restrict__ bma,
    float* __restrict__ meas_nodes)
{
  const int m = blockIdx.x, tid = threadIdx.x;
  __shared__ float bh[4][256];
  for (int i = tid; i < 4*256; i += 256)
    bh[i>>8][i&255] = beat_h[(size_t)m*4*256 + i];
  __syncthreads();
  int d = tid;
  const float* wr = Wma + (size_t)d*256;
  float bb = bma[d];
  float l[4];
#pragma unroll
  for (int n=0;n<4;++n) l[n]=bb;
#pragma unroll 4
  for (int j=0; j<256; ++j) {
    float w = wr[j];
#pragma unroll
    for (int n=0;n<4;++n) l[n] += w*bh[n][j];
  }
  float mm = fmaxf(fmaxf(l[0],l[1]), fmaxf(l[2],l[3]));
  float s = 0.f, o = 0.f;
#pragma unroll
  for (int n=0;n<4;++n) { float e = __expf(l[n]-mm); s += e; o += e*bh[n][d]; }
  meas_nodes[(size_t)m*256 + d] = o / s;
}

// ---------------- K7: measure input gates ---------------------------------
__global__ __launch_bounds__(256) void k7_mgates(
    const float* __restrict__ meas_nodes,
    const float* __restrict__ measWi, const float* __restrict__ measB,
    float* __restrict__ preM)
{
  const int dir = blockIdx.y, m0 = blockIdx.x*8, tid = threadIdx.x;
  __shared__ float nd[8][256];
  for (int i = tid; i < 8*256; i += 256)
    nd[i>>8][i&255] = meas_nodes[(size_t)m0*256 + i];
  __syncthreads();
  int g = tid;
  const float* wr = measWi + ((size_t)dir*256 + g)*256;
  float bias = measB[dir*256 + g];
  float acc[8];
#pragma unroll
  for (int n=0;n<8;++n) acc[n]=bias;
#pragma unroll 4
  for (int j=0; j<256; ++j) {
    float w = wr[j];
#pragma unroll
    for (int n=0;n<8;++n) acc[n] += w*nd[n][j];
  }
#pragma unroll
  for (int n=0;n<8;++n)
    preM[((size_t)dir*128 + (m0+n))*256 + g] = acc[n];
}

// ---------------- K8: measure recurrence (H=64) ---------------------------
__global__ __launch_bounds__(256, 2) void k8_mrec(
    const float* __restrict__ measWh,
    const float* __restrict__ preM,
    float* __restrict__ meas_h)
{
  const int dir = blockIdx.x, L = threadIdx.x;
  h16x2 w[32];
  {
    const float2* p = (const float2*)(measWh + ((size_t)dir*256 + L)*64);
#pragma unroll
    for (int c=0;c<32;++c){
      float2 v = p[c];
      w[c] = f2h2(v.x, v.y);
    }
  }
#pragma unroll
  for (int c=0;c<32;++c) pinv(w[c]);
  __shared__ __align__(16) h16 hb[64];
  __shared__ float gl[256];
  if (L < 64) hb[L] = (h16)0.f;
  float cc = 0.f;
  __syncthreads();
  const bool fwd = (dir == 0);
  for (int it = 0; it < 128; ++it) {
    const int t = fwd ? it : 127 - it;
    float pr = preM[((size_t)dir*128 + t)*256 + L];
    float ac[4] = {0.f,0.f,0.f,0.f};
#pragma unroll
    for (int c=0;c<8;++c){
      U4 hh; hh.u = *(const uint4*)&hb[c*8];
#pragma unroll
      for (int i=0;i<4;++i) ac[i] = fdot2(w[c*4+i], hh.p[i], ac[i]);
    }
    gl[L] = pr + ((ac[0]+ac[1]) + (ac[2]+ac[3]));
    __syncthreads();
    if (L < 64) {
      float gi = gl[L], gf = gl[L+64], gg = gl[L+128], go = gl[L+192];
      cc = sigm(gf)*cc + sigm(gi)*ftanh(gg);
      float h = sigm(go)*ftanh(cc);
      hb[L] = (h16)h;
      meas_h[(size_t)t*128 + dir*64 + L] = h;
    }
    __syncthreads();
  }
}

// ---------------- K9: scan known-part GEMM (pre_out + pre_fc) -------------
// pre_out written GATE-INTERLEAVED: [t][elem j][gate]
__global__ __launch_bounds__(256) void k9_scanpre(
    const float* __restrict__ note_h, const float* __restrict__ voice_h,
    const float* __restrict__ beat_h, const float* __restrict__ meas_h,
    const float* __restrict__ xf,
    const h16* __restrict__ outWiF, const h16* __restrict__ WfcKF,
    const float* __restrict__ outB, const float* __restrict__ bfc,
    float* __restrict__ pre_out, float* __restrict__ pre_fc)
{
  const int t0 = blockIdx.x*8, tid = threadIdx.x;
  __shared__ __align__(16) h16 kn[8][1416];
  const float qpm = xf[5], tp0 = xf[76], tp1 = xf[77];
  for (int i = tid; i < 8*1416; i += 256) {
    int tt = i/1416, c = i - tt*1416;
    int t = t0 + tt;
    float v;
    if (c < 512) v = note_h[(size_t)t*512 + c];
    else if (c < 768) v = beat_h[(size_t)(t>>3)*256 + (c-512)];
    else if (c < 896) v = meas_h[(size_t)(t>>5)*128 + (c-768)];
    else if (c < 1408) v = voice_h[(size_t)t*512 + (c-896)];
    else if (c == 1408) v = qpm;
    else if (c == 1409) v = tp0;
    else if (c == 1410) v = tp1;
    else v = 0.f;
    kn[tt][c] = (h16)v;
  }
  __syncthreads();
  for (int rr = 0; rr < 3; ++rr) {
    int r = (rr < 2) ? (tid + rr*256) : (512 + tid);
    if (rr == 2 && tid >= 10) break;
    const h16* wrow = (r < 512) ? (outWiF + (size_t)r*1416) : (WfcKF + (size_t)(r-512)*1416);
    float bias = (r < 512) ? outB[r] : bfc[r-512];
    float acc[8];
#pragma unroll
    for (int tt=0;tt<8;++tt) acc[tt] = bias;
    for (int cu = 0; cu < 177; ++cu) {
      U4 wv; wv.u = *(const uint4*)(wrow + cu*8);
#pragma unroll
      for (int tt=0; tt<8; ++tt) {
        U4 kv; kv.u = *(const uint4*)&kn[tt][cu*8];
#pragma unroll
        for (int i=0;i<4;++i) acc[tt] = fdot2(wv.p[i], kv.p[i], acc[tt]);
      }
    }
#pragma unroll
    for (int tt=0; tt<8; ++tt) {
      if (r < 512) pre_out[((size_t)(t0+tt)*128 + (r & 127))*4 + (r >> 7)] = acc[tt];
      else pre_fc[(size_t)(t0+tt)*16 + (r-512)] = acc[tt];
    }
  }
}

// ---------------- K9b: bt-LSTM known-part gates ---------------------------
// pre_bt written GATE-INTERLEAVED: [b][elem j][gate]
__global__ __launch_bounds__(256) void k9b_btpre(
    const float* __restrict__ beat_h, const float* __restrict__ xf,
    const float* __restrict__ btWi, const float* __restrict__ btB,
    float* __restrict__ pre_bt)
{
  const int b0 = blockIdx.x*8, tid = threadIdx.x;
  __shared__ float bh[8][256];
  __shared__ float btv[8][3];
  for (int i = tid; i < 8*256; i += 256)
    bh[i>>8][i&255] = beat_h[(size_t)b0*256 + i];
  if (tid < 24) {
    int n = tid/3, j = tid - n*3;
    btv[n][j] = xf[(size_t)(b0+n)*8*78 + 28 + j];
  }
  __syncthreads();
  const float qpm = xf[5], tp0 = xf[76], tp1 = xf[77];
  for (int gc = 0; gc < 2; ++gc) {
    int g = gc*256 + tid;
    const float* row = btWi + (size_t)g*273;
    float bias = btB[g];
    float acc[8];
#pragma unroll
    for (int n=0;n<8;++n) acc[n]=bias;
#pragma unroll 4
    for (int j = 0; j < 256; ++j) {
      float w = row[j];
#pragma unroll
      for (int n=0;n<8;++n) acc[n] += w*bh[n][j];
    }
    float w257 = row[257], w258 = row[258], w259 = row[259];
    float w260 = row[260], w261 = row[261], w262 = row[262];
#pragma unroll
    for (int n=0;n<8;++n) {
      acc[n] += w257*qpm + w258*tp0 + w259*tp1
              + w260*btv[n][0] + w261*btv[n][1] + w262*btv[n][2];
      pre_bt[((size_t)(b0+n)*128 + (g & 127))*4 + (g >> 7)] = acc[n];
    }
  }
}

// ---------------- K10: the grand sequential scan --------------------------
// Round-5 passing structure. This round's only change: the wave-0 D section
// reads WfcD/oh16 via ds_read_b128 (8 loads) instead of 64 scalar
// ds_read_u16 — same accumulation order, bit-identical results, ~8x shorter
// DS dependency chain on the step-critical path.
__global__ __launch_bounds__(512) __attribute__((amdgpu_waves_per_eu(2, 2)))
void k10_scan(
    const float* __restrict__ pre_out, const float* __restrict__ pre_fc,
    const float* __restrict__ pre_bt,
    const float* __restrict__ outWh, const float* __restrict__ btWh,
    const float* __restrict__ outWi, const float* __restrict__ btWi,
    const float* __restrict__ Wfc,
    const float* __restrict__ Wta, const float* __restrict__ bta,
    const float* __restrict__ Wt1, const float* __restrict__ bt1,
    const float* __restrict__ Wt2, const float* __restrict__ bt2,
    const float* __restrict__ yf,
    float* __restrict__ out)
{
  const int L = threadIdx.x;
  const int lane = L & 63;
  const int wid  = L >> 6;          // 0..7
  const int jl   = lane & 15;
  const int q    = lane >> 4;       // column quarter 0..3
  const int j    = wid*16 + jl;     // element 0..127
  const int row  = q*128 + j;       // gate row this copy adds seq/pre for

  // weights: 4 gates x cols [q*32, q*32+32)
  h16x2 owh[4][16], btw[4][16];
#pragma unroll
  for (int g=0; g<4; ++g) {
    const float2* p  = (const float2*)(outWh + (size_t)(g*128 + j)*128 + q*32);
    const float2* pb = (const float2*)(btWh  + (size_t)(g*128 + j)*128 + q*32);
#pragma unroll
    for (int c=0;c<16;++c){
      float2 a = p[c];  owh[g][c] = f2h2(a.x, a.y);
      float2 b = pb[c]; btw[g][c] = f2h2(b.x, b.y);
    }
  }
#pragma unroll
  for (int g=0; g<4; ++g)
#pragma unroll
    for (int c=0;c<16;++c) pinv(owh[g][c]);

  float oseq[13];
#pragma unroll
  for (int jj=0;jj<13;++jj) oseq[jj] = outWi[(size_t)row*1424 + 1408 + jj];
  float btpt = btWi[(size_t)row*273 + 256];
  float btrn[10];
#pragma unroll
  for (int d=0;d<10;++d) btrn[d] = btWi[(size_t)row*273 + 263 + d];

  __shared__ __align__(16) h16 oh16[128];
  __shared__ __align__(16) h16 th16[128];
  __shared__ __align__(16) h16 Wt1f[128*136];  // f16, padded row stride 136
  __shared__ __align__(16) h16 WfcD[10*128];
  __shared__ __align__(16) float pofc[16];
  __shared__ float ptvS;
  __shared__ float buf[8][10];
  __shared__ float rn[10], att[8][10], r1v[128], ytail[10];
  __shared__ float WfcSeq[10][13];
  __shared__ float WtaS[100], btaS[10], Wt2S[128], bt1S[128], bt2S;

  for (int i=L; i<128*128; i+=512) Wt1f[(i>>7)*136 + (i&127)] = (h16)Wt1[i];
  for (int i=L; i<10*128; i+=512)  WfcD[i] = (h16)Wfc[(size_t)(i>>7)*1552 + (i&127)];
  if (L < 100) WtaS[L] = Wta[L];
  if (L < 10)  btaS[L] = bta[L];
  if (L < 128) { Wt2S[L] = Wt2[L]; bt1S[L] = bt1[L]; }
  if (L == 0)  bt2S = bt2[0];
  if (L < 128) { oh16[L] = (h16)0.f; th16[L] = (h16)0.f; }
  if (L < 11) pofc[L] = yf[L];
  if (L >= 11 && L < 16) pofc[L] = 0.f;
  if (L == 0) ptvS = yf[0];
  if (L < 10) ytail[L] = yf[1+L];
  if (L < 80) buf[L/10][L%10] = 0.f;
  if (L < 130) WfcSeq[L/13][L%13] = Wfc[(size_t)(L/13)*1552 + 1536 + (L%13)];
  float oc = 0.f, tc = 0.f;
  float ac4[4]  = {0.f,0.f,0.f,0.f};   // Owh·h(t-1) partials (h(-1)=0)
  float acB4[4] = {0.f,0.f,0.f,0.f};   // BtWh·th(prev beat) partials
  const int dD = L >> 2, qD = L & 3;
  const float* ppo = pre_out + (size_t)j*4 + q;   // [t][j][gate] stride 512
  const float* ppb = pre_bt  + (size_t)j*4 + q;   // [b][j][gate] stride 512
  float prv  = *ppo; ppo += 512;
  float prbt = *ppb; ppb += 512;
  float prfc = (L < 40 && qD == 0) ? pre_fc[dD] : 0.f;
  const float* pp_fc = pre_fc + 16 + dD;
  __syncthreads();

  for (int t = 0; t < NT; ++t) {
    const bool isb = (t & 7) == 0;
    if (isb) {
      if (t == 0) {
        if (L < 10) rn[L] = ytail[L];
      } else {
        if (L < 80) {
          int n = L/10, d = L - n*10;
          float s = btaS[d];
#pragma unroll
          for (int jj=0;jj<10;++jj) s += buf[n][jj]*WtaS[d*10 + jj];
          att[n][d] = s;
        }
        __syncthreads();
        if (L < 10) {
          float m = att[0][L];
#pragma unroll
          for (int n=1;n<8;++n) m = fmaxf(m, att[n][L]);
          float s = 0.f, acc = 0.f;
#pragma unroll
          for (int n=0;n<8;++n) { float e = __expf(att[n][L]-m); s += e; acc += e*buf[n][L]; }
          rn[L] = acc/s;
        }
      }
      __syncthreads();
    }
    // ---- phase 1: finish gates + cells ----
    {
      float4 pf0 = *(const float4*)&pofc[0];
      float4 pf1 = *(const float4*)&pofc[4];
      float4 pf2 = *(const float4*)&pofc[8];
      float  pcc = pofc[12];
      float ex = prv;
      ex += oseq[0]*pf0.x + oseq[1]*pf0.y + oseq[2]*pf0.z + oseq[3]*pf0.w;
      ex += oseq[4]*pf1.x + oseq[5]*pf1.y + oseq[6]*pf1.z + oseq[7]*pf1.w;
      ex += oseq[8]*pf2.x + oseq[9]*pf2.y + oseq[10]*pf2.z + oseq[11]*pf2.w;
      ex += oseq[12]*pcc;
      prv = *ppo; ppo += 512;            // safe over-read at t=NT-1
      float p0 = ac4[0] + ((q==0) ? ex : 0.f);
      float p1 = ac4[1] + ((q==1) ? ex : 0.f);
      float p2 = ac4[2] + ((q==2) ? ex : 0.f);
      float p3 = ac4[3] + ((q==3) ? ex : 0.f);
      p0 += __shfl_xor(p0, 16, 64); p0 += __shfl_xor(p0, 32, 64);
      p1 += __shfl_xor(p1, 16, 64); p1 += __shfl_xor(p1, 32, 64);
      p2 += __shfl_xor(p2, 16, 64); p2 += __shfl_xor(p2, 32, 64);
      p3 += __shfl_xor(p3, 16, 64); p3 += __shfl_xor(p3, 32, 64);
      oc = sigm(p1)*oc + sigm(p0)*ftanh(p2);
      float nh = sigm(p3)*ftanh(oc);
      if (q == 0) oh16[j] = (h16)nh;
    }
    if (isb) {
      float ex = prbt + btpt*ptvS;
#pragma unroll
      for (int d=0;d<10;++d) ex += btrn[d]*rn[d];
      prbt = *ppb; ppb += 512;           // safe over-read at last beat
      float p0 = acB4[0] + ((q==0) ? ex : 0.f);
      float p1 = acB4[1] + ((q==1) ? ex : 0.f);
      float p2 = acB4[2] + ((q==2) ? ex : 0.f);
      float p3 = acB4[3] + ((q==3) ? ex : 0.f);
      p0 += __shfl_xor(p0, 16, 64); p0 += __shfl_xor(p0, 32, 64);
      p1 += __shfl_xor(p1, 16, 64); p1 += __shfl_xor(p1, 32, 64);
      p2 += __shfl_xor(p2, 16, 64); p2 += __shfl_xor(p2, 32, 64);
      p3 += __shfl_xor(p3, 16, 64); p3 += __shfl_xor(p3, 32, 64);
      tc = sigm(p1)*tc + sigm(p0)*ftanh(p2);
      float nth = sigm(p3)*ftanh(tc);
      if (q == 0) th16[j] = (h16)nth;
    }
    __syncthreads();                     // B1: oh16 (and th16) visible
    // ---- phase 2: recurrent partials for t+1 + epilogue ----
    {
      float a0=0.f,a1=0.f,a2=0.f,a3=0.f;
#pragma unroll
      for (int cb=0; cb<4; ++cb) {
        U4 hh; hh.u = *(const uint4*)&oh16[q*32 + cb*8];
#pragma unroll
        for (int i=0;i<4;++i) {
          a0 = fdot2(owh[0][cb*4+i], hh.p[i], a0);
          a1 = fdot2(owh[1][cb*4+i], hh.p[i], a1);
          a2 = fdot2(owh[2][cb*4+i], hh.p[i], a2);
          a3 = fdot2(owh[3][cb*4+i], hh.p[i], a3);
        }
      }
      ac4[0]=a0; ac4[1]=a1; ac4[2]=a2; ac4[3]=a3;
    }
    if (((t+1) & 7) == 0) {              // th16 stable until next beat's phase1
      float b0=0.f,b1=0.f,b2=0.f,b3=0.f;
#pragma unroll
      for (int cb=0; cb<4; ++cb) {
        U4 hh; hh.u = *(const uint4*)&th16[q*32 + cb*8];
#pragma unroll
        for (int i=0;i<4;++i) {
          b0 = fdot2(btw[0][cb*4+i], hh.p[i], b0);
          b1 = fdot2(btw[1][cb*4+i], hh.p[i], b1);
          b2 = fdot2(btw[2][cb*4+i], hh.p[i], b2);
          b3 = fdot2(btw[3][cb*4+i], hh.p[i], b3);
        }
      }
      acB4[0]=b0; acB4[1]=b1; acB4[2]=b2; acB4[3]=b3;
    }
    // C1: tempo hidden layer (beat steps; Wt1 f16 in LDS, th16 = new nth)
    if (isb) {
      if (L < 128) {
        float ac[4] = {0.f,0.f,0.f,0.f};
        const h16* wrow = &Wt1f[L*136];
#pragma unroll
        for (int k=0;k<16;++k){
          U4 wv; wv.u = *(const uint4*)(wrow + k*8);
          U4 hh; hh.u = *(const uint4*)&th16[k*8];
#pragma unroll
          for (int i=0;i<4;++i) ac[i] = fdot2(wv.p[i], hh.p[i], ac[i]);
        }
        float s = bt1S[L] + ((ac[0]+ac[1]) + (ac[2]+ac[3]));
        r1v[L] = fmaxf(s, 0.f);
      }
      __syncthreads();
    }
    // wave 0: C2 (ptv) + D (out_fc) + E (epilogue)
    if (L < 64) {
      float ptv_l;
      if (isb) {
        float p = Wt2S[L]*r1v[L] + Wt2S[L+64]*r1v[L+64];
#pragma unroll
        for (int sft=32; sft>0; sft>>=1) p += __shfl_xor(p, sft, 64);
        ptv_l = p + bt2S;
        if (L == 0) ptvS = ptv_l;
      } else {
        ptv_l = ptvS;
      }
      // D — vectorized loads (b128), same accumulation order as scalar form
      float s = 0.f;
      if (L < 40) {
        const h16* wr = &WfcD[dD*128 + qD*32];
#pragma unroll
        for (int k=0;k<4;++k){
          U4H wv; wv.u = *(const uint4*)(wr + k*8);
          U4H hh; hh.u = *(const uint4*)&oh16[qD*32 + k*8];
#pragma unroll
          for (int i=0;i<8;++i) s += (float)wv.h[i] * (float)hh.h[i];
        }
      }
      s += __shfl_xor(s, 1, 64);
      s += __shfl_xor(s, 2, 64);
      float e = 0.f;
      if (L < 40 && qD == 0) {
        e = prfc;
#pragma unroll
        for (int jj=0;jj<13;++jj) e += WfcSeq[dD][jj]*pofc[jj];
        prfc = *pp_fc; pp_fc += 16;      // safe over-read at t=NT-1
      }
      float ofc = s + e;                 // final at lanes 4d, d<10
      // E
      int srcE = (L >= 1 && L < 11) ? 4*(L-1) : ((L >= 11 && L < 13) ? 4*(L-11) : 0);
      float valE = __shfl(ofc, srcE, 64);
      float bval = __shfl(ofc, 4*(L & 15), 64);
      if (L == 0)      { out[(size_t)t*11] = ptv_l; pofc[0] = ptv_l; }
      else if (L < 11) { out[(size_t)t*11 + L] = valE; pofc[L] = valE; }
      else if (L < 13) { pofc[L] = valE; }
      if (L < 10) buf[t & 7][L] = bval;
    }
    __syncthreads();                     // B2: pofc/buf/ptvS for next step
  }
}

// ---------------- launcher ------------------------------------------------
extern "C" void kernel_launch(void* const* d_in, const int* in_sizes, int n_in,
                              void* d_out, int out_size, void* d_ws, size_t ws_size,
                              hipStream_t stream)
{
  const float* x      = (const float*)d_in[0];
  const float* y      = (const float*)d_in[1];
  const float* noteWi = (const float*)d_in[4];
  const float* noteWh = (const float*)d_in[5];
  const float* noteB  = (const float*)d_in[6];
  const float* voiceWi= (const float*)d_in[7];
  const float* voiceWh= (const float*)d_in[8];
  const float* voiceB = (const float*)d_in[9];
  const float* beatWi = (const float*)d_in[10];
  const float* beatWh = (const float*)d_in[11];
  const float* beatB  = (const float*)d_in[12];
  const float* measWi = (const float*)d_in[13];
  const float* measWh = (const float*)d_in[14];
  const float* measB  = (const float*)d_in[15];
  const float* Wba    = (const float*)d_in[16];
  const float* bba    = (const float*)d_in[17];
  const float* Wma    = (const float*)d_in[18];
  const float* bma    = (const float*)d_in[19];
  const float* Wta    = (const float*)d_in[20];
  const float* bta    = (const float*)d_in[21];
  const float* outWi  = (const float*)d_in[22];
  const float* outWh  = (const float*)d_in[23];
  const float* outB   = (const float*)d_in[24];
  const float* Wfc    = (const float*)d_in[25];
  const float* bfc    = (const float*)d_in[26];
  const float* btWi   = (const float*)d_in[27];
  const float* btWh   = (const float*)d_in[28];
  const float* btB    = (const float*)d_in[29];
  const float* Wt1    = (const float*)d_in[30];
  const float* bt1    = (const float*)d_in[31];
  const float* Wt2    = (const float*)d_in[32];
  const float* bt2    = (const float*)d_in[33];

  float* fws = (float*)d_ws;
  float* note_h     = fws + 0;
  float* voice_h    = fws + 2097152;
  float* beat_nodes = fws + 4194304;
  float* preB       = fws + 4456448;
  float* beat_h     = fws + 4980736;
  float* meas_nodes = fws + 5111808;
  float* preM       = fws + 5144576;
  float* meas_h     = fws + 5210112;
  float* pre_out    = fws + 5226496;
  float* pre_fc     = fws + 7323648;
  float* pre_bt     = fws + 7389184;
  h16* hws   = (h16*)(fws + 7651328);
  h16* preNV  = hws;
  h16* WhF    = hws + 16777216;
  h16* outWiF = hws + 17825792;
  h16* WfcKF  = hws + 18550784;

  float* out_outs  = (float*)d_out;
  float* out_noteh = out_outs + OUTS_OFF;

  hipLaunchKernelGGL(k0_prep, dim3(1024), dim3(256), 0, stream,
                     noteWh, voiceWh, outWi, Wfc, WhF, outWiF, WfcKF);
  hipLaunchKernelGGL(k1_xgates, dim3(256,4), dim3(256), 0, stream,
                     x, noteWi, noteB, voiceWi, voiceB, preNV);
  hipLaunchKernelGGL(k2_nvrec, dim3(4), dim3(512), 0, stream,
                     WhF, preNV, note_h, voice_h, out_noteh);
  hipLaunchKernelGGL(k3_battn, dim3(512), dim3(256), 0, stream,
                     note_h, Wba, bba, beat_nodes);
  hipLaunchKernelGGL(k4_bgates, dim3(64,2), dim3(256), 0, stream,
                     beat_nodes, beatWi, beatB, preB);
  hipLaunchKernelGGL(k5_brec, dim3(2), dim3(512), 0, stream,
                     beatWh, preB, beat_h);
  hipLaunchKernelGGL(k6_mattn, dim3(128), dim3(256), 0, stream,
                     beat_h, Wma, bma, meas_nodes);
  hipLaunchKernelGGL(k7_mgates, dim3(16,2), dim3(256), 0, stream,
                     meas_nodes, measWi, measB, preM);
  hipLaunchKernelGGL(k8_mrec, dim3(2), dim3(256), 0, stream,
                     measWh, preM, meas_h);
  hipLaunchKernelGGL(k9b_btpre, dim3(64), dim3(256), 0, stream,
                     beat_h, x, btWi, btB, pre_bt);
  hipLaunchKernelGGL(k9_scanpre, dim3(512), dim3(256), 0, stream,
                     note_h, voice_h, beat_h, meas_h, x, outWiF, WfcKF, outB, bfc, pre_out, pre_fc);
  hipLaunchKernelGGL(k10_scan, dim3(1), dim3(512), 0, stream,
                     pre_out, pre_fc, pre_bt, outWh, btWh, outWi, btWi, Wfc,
                     Wta, bta, Wt1, bt1, Wt2, bt2, y, out_outs);
}